// Round 1
// 443.482 us; speedup vs baseline: 1.0096x; 1.0096x over previous
//
#include <hip/hip_runtime.h>
#include <hip/hip_bf16.h>
#include <cstdint>
#include <cstddef>

// TeleportationAttention — R12: R11 (447us) with k_gemm1 ported to the
// 256x256 / BK=64 / 8-wave / 8-phase counted-vmcnt template (T1+T2+T3+T4+T5):
//  * extended-K: 2-term split-X becomes plain GEMM over K'=2048 (seg0=Xh,
//    seg1=Xl, W repeated); V blocks K'=1024 (1-term, unchanged math).
//  * K-half (32-wide) staging granularity -> wave-symmetric consumption ->
//    counted s_waitcnt vmcnt(4) in steady state (never 0 in main loop).
//  * m201 LDS swizzle byte ^= ((byte>>9)&1)<<5 on 128B lines; linear
//    global_load_lds dest + inverse-swizzled global source + swizzled read.
//  * raw s_barrier (no syncthreads drain), s_setprio around MFMA clusters,
//    bijective XCD blockIdx swizzle (nwg=384).
// gemm2 / softmax / gemm3 / prep identical to R11.

typedef unsigned short u16;
typedef __attribute__((ext_vector_type(8))) _Float16 half8;
typedef __attribute__((ext_vector_type(4))) float f32x4;

#define B_    4
#define S_    2048
#define D_    512
#define M_TOT (B_ * S_)   // 8192
#define KC    (2 * D_)    // 1024
#define N1    (6 * D_)    // 3072
#define LP    32          // packed pitch for gemm2/gemm3 LDS
#define RE_PLANE 4194304  // B*S*D

#define X_ELEMS  ((size_t)M_TOT * KC)
#define W_ELEMS  ((size_t)N1 * KC)
#define QK_ELEMS ((size_t)M_TOT * KC)
#define VT_ELEMS ((size_t)B_ * KC * S_)
#define AT_ELEMS ((size_t)M_TOT * S_)

__device__ __forceinline__ u16 f2h(float f) {
    _Float16 h = (_Float16)f;              // RNE
    return __builtin_bit_cast(u16, h);
}
__device__ __forceinline__ float h2f(u16 b) {
    return (float)__builtin_bit_cast(_Float16, b);
}

__device__ __forceinline__ f32x4 mfma16(half8 a, half8 b, f32x4 c) {
    return __builtin_amdgcn_mfma_f32_16x16x32_f16(a, b, c, 0, 0, 0);
}

// async global->LDS, 16B per lane.
__device__ __forceinline__ void dma16(const u16* g, u16* l) {
    __builtin_amdgcn_global_load_lds(
        (const __attribute__((address_space(1))) unsigned int*)g,
        (__attribute__((address_space(3))) unsigned int*)l,
        16, 0, 0);
}

// ---- gemm2/gemm3 staging (unchanged): [128 x 32] tile into packed LDS ----
__device__ __forceinline__ void stage_dma(const u16* __restrict__ src, int ld,
                                          int rowbase, int kbase,
                                          u16* __restrict__ dst, int tid) {
#pragma unroll
    for (int i = 0; i < 2; ++i) {
        int c = tid + 256 * i;          // 0..511
        int row = c >> 2, q = c & 3;    // 4 x 16B per row
        dma16(src + (size_t)(rowbase + row) * ld + kbase + q * 8, dst + c * 8);
    }
}

// ---- gemm1 staging: one k-half plane = 256 rows x 32 k (16 KiB), stored as
// 128 lines of 128B (rows 2L,2L+1), swizzled byte^=((byte>>9)&1)<<5.
// global_load_lds writes LDS linearly -> fetch the inverse-swizzled source
// chunk. 512 threads x 2 x 16B = 16 KiB. ld fixed = KC.
__device__ __forceinline__ void stage_half(u16* __restrict__ plane,
                                           const u16* __restrict__ src,
                                           int rowbase, int kcol, int tid) {
#pragma unroll
    for (int i = 0; i < 2; ++i) {
        int c = tid + (i << 9);                 // physical 16B chunk [0,1024)
        int c2 = c ^ (((c >> 5) & 1) << 1);     // logical chunk (involution)
        int row = ((c2 >> 3) << 1) | ((c2 >> 2) & 1);
        int ks = c2 & 3;
        dma16(src + (size_t)(rowbase + row) * KC + (kcol + ks * 8),
              plane + c * 8);
    }
}

// ---------------- diagnostic fallback ----------------
__global__ void k_diag(float* __restrict__ out, int out_size, float val) {
    int i = blockIdx.x * 256 + threadIdx.x;
    if (i < out_size && i < 4096) out[i] = val;
}

// ---------------- merged prep: fp32 -> fp16 (X split, W single, bias) ----------------
__global__ void k_prep(const float* __restrict__ xr, const float* __restrict__ xi,
                       const float* __restrict__ Wqr, const float* __restrict__ Wqi,
                       const float* __restrict__ Wkr, const float* __restrict__ Wki,
                       const float* __restrict__ Wvr, const float* __restrict__ Wvi,
                       const float* __restrict__ bqr, const float* __restrict__ bqi,
                       const float* __restrict__ bkr, const float* __restrict__ bki,
                       const float* __restrict__ bvr, const float* __restrict__ bvi,
                       u16* __restrict__ Xh, u16* __restrict__ Xl,
                       u16* __restrict__ Wh, float* __restrict__ bc) {
    int gb = blockIdx.x;
    int tid = threadIdx.x;
    if (gb < 16384) {
        int id = gb * 256 + tid;                 // [0, 4194304)
        int m = id >> 9, d = id & 511;
        size_t o = (size_t)m * KC + d;
        if (o + D_ >= X_ELEMS) return;
        float vr = xr[id], vi = xi[id];
        u16 h;
        h = f2h(vr); Xh[o] = h;        Xl[o] = f2h(vr - h2f(h));
        h = f2h(vi); Xh[o + D_] = h;   Xl[o + D_] = f2h(vi - h2f(h));
    } else if (gb < 16384 + 12288) {
        int id = (gb - 16384) * 256 + tid;       // [0, 3145728)
        int n = id >> 10, k = id & 1023;
        int q = n >> 9, e = n & 511;
        int half = k >> 9, d = k & 511;
        const float* Wre = (q < 2) ? Wqr : ((q < 4) ? Wkr : Wvr);
        const float* Wim = (q < 2) ? Wqi : ((q < 4) ? Wki : Wvi);
        size_t src = (size_t)e * D_ + d;
        float v;
        if ((q & 1) == 0) v = half ? -Wim[src] : Wre[src];
        else              v = half ?  Wre[src] : Wim[src];
        if ((size_t)id < W_ELEMS) Wh[id] = f2h(v);
    } else {
        int id = (gb - 16384 - 12288) * 256 + tid;  // [0, 3072)
        if (id >= N1) return;
        int q = id >> 9, e = id & 511;
        const float* src = (q == 0) ? bqr : (q == 1) ? bqi : (q == 2) ? bkr
                         : (q == 3) ? bki : (q == 4) ? bvr : bvi;
        bc[id] = src[e];
    }
}

// ---------------- GEMM1: projections (256^2 8-phase template) ----------------
// One tile-phase body. P = LDS buffer parity of the CURRENT tile; when STG,
// stages tile t+1 halves in order A-k0,B-k0,A-k1,B-k1 with vmcnt(4) at the
// two odd phases; without STG (last tile) drains with vmcnt(0) at phase 1.
#define GTILE(P, STG, SRCA, KA)                                               \
  {                                                                           \
    const int p_ = (P);                                                       \
    _Pragma("unroll")                                                         \
    for (int q = 0; q < 4; ++q) {                                             \
      const int kh = q >> 1, mg = q & 1;                                      \
      const u16* pa = &lds[(p_ << 2) | kh][0];                                \
      const u16* pb = &lds[(p_ << 2) | 2 | kh][0];                            \
      half8 a[4];                                                             \
      if (mg == 0) {                                                          \
        _Pragma("unroll")                                                     \
        for (int j = 0; j < 4; ++j)                                           \
          b[j] = *(const half8*)(pb + boffs + j * 512);                       \
      }                                                                       \
      _Pragma("unroll")                                                       \
      for (int i = 0; i < 4; ++i)                                             \
        a[i] = *(const half8*)(pa + aoffs + (mg * 4 + i) * 512);              \
      if (STG) {                                                              \
        const int xp = (p_ ^ 1) << 2;                                         \
        if (q == 0) stage_half(&lds[xp][0], SRCA, mb, (KA), tid);             \
        if (q == 1) stage_half(&lds[xp | 2][0], Wh, nb, (KA), tid);           \
        if (q == 2) stage_half(&lds[xp | 1][0], SRCA, mb, (KA) + 32, tid);    \
        if (q == 3) stage_half(&lds[xp | 3][0], Wh, nb, (KA) + 32, tid);      \
        if (q & 1) asm volatile("s_waitcnt vmcnt(4)" ::: "memory");           \
      } else if (q == 1) {                                                    \
        asm volatile("s_waitcnt vmcnt(0)" ::: "memory");                      \
      }                                                                       \
      __builtin_amdgcn_s_barrier();                                           \
      __builtin_amdgcn_s_setprio(1);                                          \
      _Pragma("unroll")                                                       \
      for (int j = 0; j < 4; ++j) {                                           \
        _Pragma("unroll")                                                     \
        for (int i = 0; i < 4; ++i)                                           \
          acc[mg * 4 + i][j] = mfma16(a[i], b[j], acc[mg * 4 + i][j]);        \
      }                                                                       \
      __builtin_amdgcn_s_setprio(0);                                          \
      __builtin_amdgcn_s_barrier();                                           \
    }                                                                         \
  }

__global__ __launch_bounds__(512, 2) void k_gemm1(
    const u16* __restrict__ Xh, const u16* __restrict__ Xl,
    const u16* __restrict__ Wh,
    const float* __restrict__ bc,
    u16* __restrict__ Qh, u16* __restrict__ Ql,
    u16* __restrict__ Kh, u16* __restrict__ Kl,
    u16* __restrict__ VT) {
    // [buf p][mat A=0/B=1][k-half] 16 KiB planes -> 128 KiB total
    __shared__ __attribute__((aligned(16))) u16 lds[8][8192];
    int tid = threadIdx.x;

    // T1: bijective XCD swizzle; nwg = 12*32 = 384, 384 % 8 == 0
    int orig = blockIdx.y * 12 + blockIdx.x;
    int swz = (orig & 7) * 48 + (orig >> 3);
    int bx = swz % 12, by = swz / 12;
    int nb = bx * 256, mb = by * 256;
    int g = bx >> 2;                 // 0:Q 1:K 2:V (block-uniform)
    bool vblk = (g == 2);
    int NT = vblk ? 16 : 32;         // extended-K tiles of 64

    int lane = tid & 63, wave = tid >> 6;
    int wm = (wave >> 2) * 128, wn = (wave & 3) * 64;   // 2x4 waves
    int lr = lane & 15, lq = lane >> 4;
    // swizzled read offset: phys chunk = (row*4 + lq) ^ (2 if row&8); row&8 == lr&8
    int lqs8 = (lq ^ (((lr >> 3) & 1) << 1)) * 8;
    int aoffs = (wm + lr) * 32 + lqs8;
    int boffs = (wn + lr) * 32 + lqs8;

    f32x4 acc[8][4] = {};
    half8 b[4];

    // prologue: stage tile 0 (A-k0, B-k0, A-k1, B-k1), publish k0 planes
    stage_half(&lds[0][0], Xh, mb, 0, tid);
    stage_half(&lds[2][0], Wh, nb, 0, tid);
    stage_half(&lds[1][0], Xh, mb, 32, tid);
    stage_half(&lds[3][0], Wh, nb, 32, tid);
    asm volatile("s_waitcnt vmcnt(4)" ::: "memory");
    __builtin_amdgcn_s_barrier();

    for (int t = 0; t < NT - 1; ++t) {
        int tt = t + 1;
        const u16* srcA = (tt < 16) ? Xh : Xl;   // segment 0: Xh, 1: Xl
        int ka = (tt & 15) << 6;                 // W repeats per segment
        GTILE(t & 1, 1, srcA, ka);
    }
    GTILE((NT - 1) & 1, 0, Xh, 0);               // last tile: drain, no stage

    // epilogue (same math as R11; i extended to 8 for 256-row tile)
#pragma unroll
    for (int j = 0; j < 4; ++j) {
        int n_g = nb + wn + j * 16 + lr;
        float bias = bc[n_g];
        int c = n_g & 1023;
#pragma unroll
        for (int i = 0; i < 8; ++i) {
            int m0 = mb + wm + i * 16 + lq * 4;
            if (vblk) {
                int bidx = m0 >> 11, s0 = m0 & 2047;
                u16 pk[4];
#pragma unroll
                for (int r = 0; r < 4; ++r) pk[r] = f2h(acc[i][j][r] + bias);
                size_t idx = ((size_t)(bidx * KC + c)) * S_ + s0;
                if (idx + 3 < VT_ELEMS)
                    *(ushort4*)&VT[idx] = make_ushort4(pk[0], pk[1], pk[2], pk[3]);
            } else {
                u16* dh = g ? Kh : Qh;
                u16* dl = g ? Kl : Ql;
#pragma unroll
                for (int r = 0; r < 4; ++r) {
                    float v = acc[i][j][r] + bias;
                    u16 h = f2h(v);
                    size_t idx = (size_t)(m0 + r) * KC + c;
                    if (idx < QK_ELEMS) {
                        dh[idx] = h;
                        dl[idx] = f2h(v - h2f(h));
                    }
                }
            }
        }
    }
}

// ---------------- GEMM2: scores (3-term: QhKh + QlKh + QhKl) ----------------
__global__ __launch_bounds__(256) void k_gemm2(
    const u16* __restrict__ Qh, const u16* __restrict__ Ql,
    const u16* __restrict__ Kh, const u16* __restrict__ Kl,
    float* __restrict__ SC, int zbase) {
    __shared__ __attribute__((aligned(16))) u16 sAh[128 * LP], sAl[128 * LP],
                                                sBh[128 * LP], sBl[128 * LP];
    int tid = threadIdx.x;
    int nb = blockIdx.x * 128, mb = blockIdx.y * 128;
    int z = zbase + blockIdx.z;
    const u16* Ah = Qh + (size_t)z * S_ * KC;
    const u16* Al = Ql + (size_t)z * S_ * KC;
    const u16* Bh = Kh + (size_t)z * S_ * KC;
    const u16* Bl = Kl + (size_t)z * S_ * KC;
    int lane = tid & 63, wave = tid >> 6;
    int wm = (wave >> 1) * 64, wn = (wave & 1) * 64;
    int lr = lane & 15, lq = lane >> 4;
    f32x4 acc[4][4] = {};

    for (int k0 = 0; k0 < KC; k0 += 32) {
        __syncthreads();
        stage_dma(Ah, KC, mb, k0, sAh, tid);
        stage_dma(Al, KC, mb, k0, sAl, tid);
        stage_dma(Bh, KC, nb, k0, sBh, tid);
        stage_dma(Bl, KC, nb, k0, sBl, tid);
        __syncthreads();
        half8 ah[4], al[4], bh[4], bl[4];
#pragma unroll
        for (int i = 0; i < 4; ++i) {
            int ra = wm + i * 16 + lr;
            ah[i] = *(const half8*)&sAh[ra * LP + lq * 8];
            al[i] = *(const half8*)&sAl[ra * LP + lq * 8];
            int rb = wn + i * 16 + lr;
            bh[i] = *(const half8*)&sBh[rb * LP + lq * 8];
            bl[i] = *(const half8*)&sBl[rb * LP + lq * 8];
        }
#pragma unroll
        for (int i = 0; i < 4; ++i)
#pragma unroll
            for (int j = 0; j < 4; ++j) {
                acc[i][j] = mfma16(ah[i], bh[j], acc[i][j]);
                acc[i][j] = mfma16(al[i], bh[j], acc[i][j]);
                acc[i][j] = mfma16(ah[i], bl[j], acc[i][j]);
            }
    }

    size_t sc_limit = (size_t)gridDim.z * S_ * S_;
#pragma unroll
    for (int j = 0; j < 4; ++j) {
        int t = nb + wn + j * 16 + lr;
#pragma unroll
        for (int i = 0; i < 4; ++i) {
            int s0 = mb + wm + i * 16 + lq * 4;
#pragma unroll
            for (int r = 0; r < 4; ++r) {
                size_t idx = ((size_t)blockIdx.z * S_ + s0 + r) * S_ + t;
                if (idx < sc_limit) SC[idx] = acc[i][j][r];
            }
        }
    }
}

// ---------------- softmax: SC fp32 -> AT fp16 ----------------
__global__ __launch_bounds__(256) void k_softmax(const float* __restrict__ SC,
                                                 u16* __restrict__ AT, int zbase) {
    int row = blockIdx.x;
    const float* src = SC + (size_t)row * S_;
    size_t drow = (size_t)zbase * S_ + row;
    u16* dst = AT + drow * S_;
    int tid = threadIdx.x;
    float v[8];
#pragma unroll
    for (int i = 0; i < 8; ++i) v[i] = src[tid + i * 256];
    float m = v[0];
#pragma unroll
    for (int i = 1; i < 8; ++i) m = fmaxf(m, v[i]);
    for (int off = 32; off > 0; off >>= 1) m = fmaxf(m, __shfl_down(m, off));
    __shared__ float redm[4], reds[4];
    if ((tid & 63) == 0) redm[tid >> 6] = m;
    __syncthreads();
    m = fmaxf(fmaxf(redm[0], redm[1]), fmaxf(redm[2], redm[3]));
    float s = 0.f;
#pragma unroll
    for (int i = 0; i < 8; ++i) { v[i] = __expf(v[i] - m); s += v[i]; }
    for (int off = 32; off > 0; off >>= 1) s += __shfl_down(s, off);
    if ((tid & 63) == 0) reds[tid >> 6] = s;
    __syncthreads();
    float inv = 1.0f / (reds[0] + reds[1] + reds[2] + reds[3]);
    if (drow * S_ + 2047 < AT_ELEMS) {
#pragma unroll
        for (int i = 0; i < 8; ++i) dst[tid + i * 256] = f2h(v[i] * inv);
    }
}

// ---------------- GEMM3: out = attn @ Vcat (plain fp16), planar epilogue ----------------
__global__ __launch_bounds__(256) void k_gemm3(
    const u16* __restrict__ AT, const u16* __restrict__ VT,
    float* __restrict__ out, int out_size, int full) {
    __shared__ __attribute__((aligned(16))) u16 sA[128 * LP], sB[128 * LP];
    int tid = threadIdx.x;
    int nb = blockIdx.x * 128, mb = blockIdx.y * 128, z = blockIdx.z;
    const u16* Abase = AT + (size_t)z * S_ * S_;
    const u16* Bbase = VT + (size_t)z * KC * S_;
    int lane = tid & 63, wave = tid >> 6;
    int wm = (wave >> 1) * 64, wn = (wave & 1) * 64;
    int lr = lane & 15, lq = lane >> 4;
    f32x4 acc[4][4] = {};

    for (int k0 = 0; k0 < S_; k0 += 32) {
        __syncthreads();
        stage_dma(Abase, S_, mb, k0, sA, tid);
        stage_dma(Bbase, S_, nb, k0, sB, tid);
        __syncthreads();
        half8 a[4], b[4];
#pragma unroll
        for (int i = 0; i < 4; ++i) {
            a[i] = *(const half8*)&sA[(wm + i * 16 + lr) * LP + lq * 8];
            b[i] = *(const half8*)&sB[(wn + i * 16 + lr) * LP + lq * 8];
        }
#pragma unroll
        for (int i = 0; i < 4; ++i)
#pragma unroll
            for (int j = 0; j < 4; ++j)
                acc[i][j] = mfma16(a[i], b[j], acc[i][j]);
    }

#pragma unroll
    for (int j = 0; j < 4; ++j) {
        int f = nb + wn + j * 16 + lr;
#pragma unroll
        for (int i = 0; i < 4; ++i) {
            int s0 = mb + wm + i * 16 + lq * 4;
#pragma unroll
            for (int r = 0; r < 4; ++r) {
                size_t base = ((size_t)z * S_ + s0 + r) * D_;
                if (f < D_) {
                    size_t o = base + f;
                    if (o < (size_t)out_size) out[o] = acc[i][j][r];
                } else if (full) {
                    size_t o = (size_t)RE_PLANE + base + (f - D_);
                    if (o < (size_t)out_size) out[o] = acc[i][j][r];
                }
            }
        }
    }
}

// ---------------- launch ----------------

extern "C" void kernel_launch(void* const* d_in, const int* in_sizes, int n_in,
                              void* d_out, int out_size, void* d_ws, size_t ws_size,
                              hipStream_t stream) {
    (void)in_sizes; (void)n_in;
    const float* xr  = (const float*)d_in[0];
    const float* xi  = (const float*)d_in[1];
    const float* Wqr = (const float*)d_in[2];
    const float* Wqi = (const float*)d_in[3];
    const float* bqr = (const float*)d_in[4];
    const float* bqi = (const float*)d_in[5];
    const float* Wkr = (const float*)d_in[6];
    const float* Wki = (const float*)d_in[7];
    const float* bkr = (const float*)d_in[8];
    const float* bki = (const float*)d_in[9];
    const float* Wvr = (const float*)d_in[10];
    const float* Wvi = (const float*)d_in[11];
    const float* bvr = (const float*)d_in[12];
    const float* bvi = (const float*)d_in[13];
    float* out = (float*)d_out;

    constexpr size_t SZ_X  = X_ELEMS * 2;          // 16 MiB each (Xh, Xl)
    constexpr size_t SZ_W  = W_ELEMS * 2;          // 6 MiB
    constexpr size_t SZ_BC = (size_t)N1 * 4;
    constexpr size_t SZ_QK = QK_ELEMS * 2;         // 16 MiB each (Qh,Ql,Kh,Kl)
    constexpr size_t SZ_VT = VT_ELEMS * 2;         // 16 MiB
    constexpr size_t SZ_SC_B = (size_t)S_ * S_ * 4;  // 16 MiB per batch

    char* p = (char*)d_ws;
    size_t off = 0;
    auto take = [&](size_t sz) {
        char* r = p + off;
        off += (sz + 255) & ~(size_t)255;
        return r;
    };
    u16*   Xh = (u16*)take(SZ_X);
    u16*   Xl = (u16*)take(SZ_X);
    u16*   Wh = (u16*)take(SZ_W);
    float* bc = (float*)take(SZ_BC);
    u16*   Qh = (u16*)take(SZ_QK);
    u16*   Ql = (u16*)take(SZ_QK);
    u16*   Kh = (u16*)take(SZ_QK);
    u16*   Kl = (u16*)take(SZ_QK);
    u16*   VT = (u16*)take(SZ_VT);
    u16*   AT = Xh;  // aliases Xh+Xl (32 MiB, dead after gemm1); no Qh overlap
    float* SC = (float*)(p + off);

    int nz = 0;
    if (ws_size > off) nz = (int)((ws_size - off) / SZ_SC_B);
    if (nz > B_) nz = B_;
    if (nz < 1) {
        k_diag<<<16, 256, 0, stream>>>(out, out_size, 1000.0f + (float)(ws_size >> 20));
        return;
    }

    int full = (out_size >= 2 * RE_PLANE) ? 1 : 0;

    k_prep<<<16384 + 12288 + 12, 256, 0, stream>>>(
        xr, xi, Wqr, Wqi, Wkr, Wki, Wvr, Wvi,
        bqr, bqi, bkr, bki, bvr, bvi, Xh, Xl, Wh, bc);
    k_gemm1<<<dim3(N1 / 256, M_TOT / 256), 512, 0, stream>>>(Xh, Xl, Wh, bc, Qh, Ql, Kh, Kl, VT);

    for (int z0 = 0; z0 < B_; z0 += nz) {
        int zc = (B_ - z0 < nz) ? (B_ - z0) : nz;
        k_gemm2<<<dim3(S_ / 128, S_ / 128, zc), 256, 0, stream>>>(Qh, Ql, Kh, Kl, SC, z0);
        k_softmax<<<zc * S_, 256, 0, stream>>>(SC, AT, z0);
    }
    k_gemm3<<<dim3(KC / 128, S_ / 128, B_), 256, 0, stream>>>(AT, VT, out, out_size, full);
}

// Round 2
// 437.025 us; speedup vs baseline: 1.0245x; 1.0148x over previous
//
#include <hip/hip_runtime.h>
#include <hip/hip_bf16.h>
#include <cstdint>
#include <cstddef>

// TeleportationAttention — R13: R12 with k_gemm1's prefetch DEEPENED.
// R12 post-mortem: swizzle worked (bank conflicts 8.4M->0) but vmcnt(4)
// waited on loads issued only 2-3 phases earlier (~350 cyc) < load latency
// (200-900 cyc) -> 67% stall, MfmaUtil 21%. R13 keeps 2 LDS buffers but
// stages 6 phases ahead, exploiting that a k-half plane dies 2 phases
// before its buffer:
//   (t,q0/q1): stage tile t+1's k1 planes (buf p^1, planes 1/3)
//   (t,q2/q3): stage tile t+2's k0 planes (buf p,   planes 0/2)
//   waits: vmcnt(8) at q1/q3 (12 in flight, drain oldest 4 = planes
//   needed next phase, issued 5-6 phases ago). Tail: vmcnt(8/4) then (0).
// Everything else identical to R12 (which matched R11 accuracy, absmax 0.1289).

typedef unsigned short u16;
typedef __attribute__((ext_vector_type(8))) _Float16 half8;
typedef __attribute__((ext_vector_type(4))) float f32x4;

#define B_    4
#define S_    2048
#define D_    512
#define M_TOT (B_ * S_)   // 8192
#define KC    (2 * D_)    // 1024
#define N1    (6 * D_)    // 3072
#define LP    32          // packed pitch for gemm2/gemm3 LDS
#define RE_PLANE 4194304  // B*S*D

#define X_ELEMS  ((size_t)M_TOT * KC)
#define W_ELEMS  ((size_t)N1 * KC)
#define QK_ELEMS ((size_t)M_TOT * KC)
#define VT_ELEMS ((size_t)B_ * KC * S_)
#define AT_ELEMS ((size_t)M_TOT * S_)

__device__ __forceinline__ u16 f2h(float f) {
    _Float16 h = (_Float16)f;              // RNE
    return __builtin_bit_cast(u16, h);
}
__device__ __forceinline__ float h2f(u16 b) {
    return (float)__builtin_bit_cast(_Float16, b);
}

__device__ __forceinline__ f32x4 mfma16(half8 a, half8 b, f32x4 c) {
    return __builtin_amdgcn_mfma_f32_16x16x32_f16(a, b, c, 0, 0, 0);
}

// async global->LDS, 16B per lane.
__device__ __forceinline__ void dma16(const u16* g, u16* l) {
    __builtin_amdgcn_global_load_lds(
        (const __attribute__((address_space(1))) unsigned int*)g,
        (__attribute__((address_space(3))) unsigned int*)l,
        16, 0, 0);
}

// ---- gemm2/gemm3 staging (unchanged): [128 x 32] tile into packed LDS ----
__device__ __forceinline__ void stage_dma(const u16* __restrict__ src, int ld,
                                          int rowbase, int kbase,
                                          u16* __restrict__ dst, int tid) {
#pragma unroll
    for (int i = 0; i < 2; ++i) {
        int c = tid + 256 * i;          // 0..511
        int row = c >> 2, q = c & 3;    // 4 x 16B per row
        dma16(src + (size_t)(rowbase + row) * ld + kbase + q * 8, dst + c * 8);
    }
}

// ---- gemm1 staging: one k-half plane = 256 rows x 32 k (16 KiB), stored as
// 128 lines of 128B (rows 2L,2L+1), swizzled byte^=((byte>>9)&1)<<5.
// global_load_lds writes LDS linearly -> fetch the inverse-swizzled source
// chunk. 512 threads x 2 x 16B = 16 KiB. ld fixed = KC.
__device__ __forceinline__ void stage_half(u16* __restrict__ plane,
                                           const u16* __restrict__ src,
                                           int rowbase, int kcol, int tid) {
#pragma unroll
    for (int i = 0; i < 2; ++i) {
        int c = tid + (i << 9);                 // physical 16B chunk [0,1024)
        int c2 = c ^ (((c >> 5) & 1) << 1);     // logical chunk (involution)
        int row = ((c2 >> 3) << 1) | ((c2 >> 2) & 1);
        int ks = c2 & 3;
        dma16(src + (size_t)(rowbase + row) * KC + (kcol + ks * 8),
              plane + c * 8);
    }
}

#define VMW(N) asm volatile("s_waitcnt vmcnt(" #N ")" ::: "memory")

// ---------------- diagnostic fallback ----------------
__global__ void k_diag(float* __restrict__ out, int out_size, float val) {
    int i = blockIdx.x * 256 + threadIdx.x;
    if (i < out_size && i < 4096) out[i] = val;
}

// ---------------- merged prep: fp32 -> fp16 (X split, W single, bias) ----------------
__global__ void k_prep(const float* __restrict__ xr, const float* __restrict__ xi,
                       const float* __restrict__ Wqr, const float* __restrict__ Wqi,
                       const float* __restrict__ Wkr, const float* __restrict__ Wki,
                       const float* __restrict__ Wvr, const float* __restrict__ Wvi,
                       const float* __restrict__ bqr, const float* __restrict__ bqi,
                       const float* __restrict__ bkr, const float* __restrict__ bki,
                       const float* __restrict__ bvr, const float* __restrict__ bvi,
                       u16* __restrict__ Xh, u16* __restrict__ Xl,
                       u16* __restrict__ Wh, float* __restrict__ bc) {
    int gb = blockIdx.x;
    int tid = threadIdx.x;
    if (gb < 16384) {
        int id = gb * 256 + tid;                 // [0, 4194304)
        int m = id >> 9, d = id & 511;
        size_t o = (size_t)m * KC + d;
        if (o + D_ >= X_ELEMS) return;
        float vr = xr[id], vi = xi[id];
        u16 h;
        h = f2h(vr); Xh[o] = h;        Xl[o] = f2h(vr - h2f(h));
        h = f2h(vi); Xh[o + D_] = h;   Xl[o + D_] = f2h(vi - h2f(h));
    } else if (gb < 16384 + 12288) {
        int id = (gb - 16384) * 256 + tid;       // [0, 3145728)
        int n = id >> 10, k = id & 1023;
        int q = n >> 9, e = n & 511;
        int half = k >> 9, d = k & 511;
        const float* Wre = (q < 2) ? Wqr : ((q < 4) ? Wkr : Wvr);
        const float* Wim = (q < 2) ? Wqi : ((q < 4) ? Wki : Wvi);
        size_t src = (size_t)e * D_ + d;
        float v;
        if ((q & 1) == 0) v = half ? -Wim[src] : Wre[src];
        else              v = half ?  Wre[src] : Wim[src];
        if ((size_t)id < W_ELEMS) Wh[id] = f2h(v);
    } else {
        int id = (gb - 16384 - 12288) * 256 + tid;  // [0, 3072)
        if (id >= N1) return;
        int q = id >> 9, e = id & 511;
        const float* src = (q == 0) ? bqr : (q == 1) ? bqi : (q == 2) ? bkr
                         : (q == 3) ? bki : (q == 4) ? bvr : bvi;
        bc[id] = src[e];
    }
}

// ---------------- GEMM1: projections (256^2, deep-prefetch 8-phase) ----------------
// Phase (t,q): kh=q>>1 selects k-half, mg=q&1 selects acc row-group.
// STG0/STG1 stage tile t+1's k1; STG2/STG3 stage tile t+2's k0.
// W1/W3 are the counted waits (vmcnt drains in issue order; the drained
// quartet is exactly the pair of planes consumed in the NEXT phase pair).
#define GTILE(P, STG0, STG1, W1, STG2, STG3, W3)                              \
  {                                                                           \
    const int p_ = (P);                                                       \
    _Pragma("unroll")                                                         \
    for (int q = 0; q < 4; ++q) {                                             \
      const int kh = q >> 1, mg = q & 1;                                      \
      const u16* pa = &lds[(p_ << 2) | kh][0];                                \
      const u16* pb = &lds[(p_ << 2) | 2 | kh][0];                            \
      half8 a[4];                                                             \
      if (mg == 0) {                                                          \
        _Pragma("unroll")                                                     \
        for (int j = 0; j < 4; ++j)                                           \
          b[j] = *(const half8*)(pb + boffs + j * 512);                       \
      }                                                                       \
      _Pragma("unroll")                                                       \
      for (int i = 0; i < 4; ++i)                                             \
        a[i] = *(const half8*)(pa + aoffs + (mg * 4 + i) * 512);              \
      if (q == 0)      { STG0; }                                              \
      else if (q == 1) { STG1; W1; }                                          \
      else if (q == 2) { STG2; }                                              \
      else             { STG3; W3; }                                          \
      __builtin_amdgcn_s_barrier();                                           \
      __builtin_amdgcn_s_setprio(1);                                          \
      _Pragma("unroll")                                                       \
      for (int j = 0; j < 4; ++j) {                                           \
        _Pragma("unroll")                                                     \
        for (int i = 0; i < 4; ++i)                                           \
          acc[mg * 4 + i][j] = mfma16(a[i], b[j], acc[mg * 4 + i][j]);        \
      }                                                                       \
      __builtin_amdgcn_s_setprio(0);                                          \
      __builtin_amdgcn_s_barrier();                                           \
    }                                                                         \
  }

__global__ __launch_bounds__(512, 2) void k_gemm1(
    const u16* __restrict__ Xh, const u16* __restrict__ Xl,
    const u16* __restrict__ Wh,
    const float* __restrict__ bc,
    u16* __restrict__ Qh, u16* __restrict__ Ql,
    u16* __restrict__ Kh, u16* __restrict__ Kl,
    u16* __restrict__ VT) {
    // [buf p][mat A=0/B=1][k-half] 16 KiB planes -> 128 KiB total
    __shared__ __attribute__((aligned(16))) u16 lds[8][8192];
    int tid = threadIdx.x;

    // T1: bijective XCD swizzle; nwg = 12*32 = 384, 384 % 8 == 0
    int orig = blockIdx.y * 12 + blockIdx.x;
    int swz = (orig & 7) * 48 + (orig >> 3);
    int bx = swz % 12, by = swz / 12;
    int nb = bx * 256, mb = by * 256;
    int g = bx >> 2;                 // 0:Q 1:K 2:V (block-uniform)
    bool vblk = (g == 2);
    int NT = vblk ? 16 : 32;         // extended-K tiles of 64

    int lane = tid & 63, wave = tid >> 6;
    int wm = (wave >> 2) * 128, wn = (wave & 3) * 64;   // 2x4 waves
    int lr = lane & 15, lq = lane >> 4;
    // swizzled read offset: phys chunk = (row*4 + lq) ^ (2 if row&8); row&8 == lr&8
    int lqs8 = (lq ^ (((lr >> 3) & 1) << 1)) * 8;
    int aoffs = (wm + lr) * 32 + lqs8;
    int boffs = (wn + lr) * 32 + lqs8;

    f32x4 acc[8][4] = {};
    half8 b[4];

    // prologue: tile 0 (both k-halves) + tile 1 k0  => 12 loads in flight
    stage_half(&lds[0][0], Xh, mb, 0, tid);    // A(0,k0)
    stage_half(&lds[2][0], Wh, nb, 0, tid);    // B(0,k0)
    stage_half(&lds[1][0], Xh, mb, 32, tid);   // A(0,k1)
    stage_half(&lds[3][0], Wh, nb, 32, tid);   // B(0,k1)
    stage_half(&lds[4][0], Xh, mb, 64, tid);   // A(1,k0) -> buf1 plane0
    stage_half(&lds[6][0], Wh, nb, 64, tid);   // B(1,k0) -> buf1 plane2
    VMW(8);                                    // A/B(0,k0) landed
    __builtin_amdgcn_s_barrier();

    for (int t = 0; t < NT - 2; ++t) {
        const int p = t & 1;
        const u16* s1 = (!vblk && (t + 1) >= 16) ? Xl : Xh;
        const int k1o = (((t + 1) & 15) << 6) + 32;
        const u16* s2 = (!vblk && (t + 2) >= 16) ? Xl : Xh;
        const int k2o = ((t + 2) & 15) << 6;
        GTILE(p,
              stage_half(&lds[((p ^ 1) << 2) | 1][0], s1, mb, k1o, tid),
              stage_half(&lds[((p ^ 1) << 2) | 3][0], Wh, nb, k1o, tid),
              VMW(8),
              stage_half(&lds[(p << 2) | 0][0], s2, mb, k2o, tid),
              stage_half(&lds[(p << 2) | 2][0], Wh, nb, k2o, tid),
              VMW(8));
    }
    {   // t = NT-2: only tile NT-1's k1 remains to stage
        const int p = (NT - 2) & 1;            // 0 (NT even)
        const u16* s1 = vblk ? Xh : Xl;        // tile NT-1: seg1 for Q/K
        const int k1o = (((NT - 1) & 15) << 6) + 32;
        GTILE(p,
              stage_half(&lds[((p ^ 1) << 2) | 1][0], s1, mb, k1o, tid),
              stage_half(&lds[((p ^ 1) << 2) | 3][0], Wh, nb, k1o, tid),
              VMW(8),
              (void)0, (void)0,
              VMW(4));                         // A/B(NT-1,k0) landed
    }
    {   // t = NT-1: drain
        const int p = (NT - 1) & 1;            // 1
        GTILE(p, (void)0, (void)0, VMW(0), (void)0, (void)0, (void)0);
    }

    // epilogue (same math as R11; i extended to 8 for 256-row tile)
#pragma unroll
    for (int j = 0; j < 4; ++j) {
        int n_g = nb + wn + j * 16 + lr;
        float bias = bc[n_g];
        int c = n_g & 1023;
#pragma unroll
        for (int i = 0; i < 8; ++i) {
            int m0 = mb + wm + i * 16 + lq * 4;
            if (vblk) {
                int bidx = m0 >> 11, s0 = m0 & 2047;
                u16 pk[4];
#pragma unroll
                for (int r = 0; r < 4; ++r) pk[r] = f2h(acc[i][j][r] + bias);
                size_t idx = ((size_t)(bidx * KC + c)) * S_ + s0;
                if (idx + 3 < VT_ELEMS)
                    *(ushort4*)&VT[idx] = make_ushort4(pk[0], pk[1], pk[2], pk[3]);
            } else {
                u16* dh = g ? Kh : Qh;
                u16* dl = g ? Kl : Ql;
#pragma unroll
                for (int r = 0; r < 4; ++r) {
                    float v = acc[i][j][r] + bias;
                    u16 h = f2h(v);
                    size_t idx = (size_t)(m0 + r) * KC + c;
                    if (idx < QK_ELEMS) {
                        dh[idx] = h;
                        dl[idx] = f2h(v - h2f(h));
                    }
                }
            }
        }
    }
}

// ---------------- GEMM2: scores (3-term: QhKh + QlKh + QhKl) ----------------
__global__ __launch_bounds__(256) void k_gemm2(
    const u16* __restrict__ Qh, const u16* __restrict__ Ql,
    const u16* __restrict__ Kh, const u16* __restrict__ Kl,
    float* __restrict__ SC, int zbase) {
    __shared__ __attribute__((aligned(16))) u16 sAh[128 * LP], sAl[128 * LP],
                                                sBh[128 * LP], sBl[128 * LP];
    int tid = threadIdx.x;
    int nb = blockIdx.x * 128, mb = blockIdx.y * 128;
    int z = zbase + blockIdx.z;
    const u16* Ah = Qh + (size_t)z * S_ * KC;
    const u16* Al = Ql + (size_t)z * S_ * KC;
    const u16* Bh = Kh + (size_t)z * S_ * KC;
    const u16* Bl = Kl + (size_t)z * S_ * KC;
    int lane = tid & 63, wave = tid >> 6;
    int wm = (wave >> 1) * 64, wn = (wave & 1) * 64;
    int lr = lane & 15, lq = lane >> 4;
    f32x4 acc[4][4] = {};

    for (int k0 = 0; k0 < KC; k0 += 32) {
        __syncthreads();
        stage_dma(Ah, KC, mb, k0, sAh, tid);
        stage_dma(Al, KC, mb, k0, sAl, tid);
        stage_dma(Bh, KC, nb, k0, sBh, tid);
        stage_dma(Bl, KC, nb, k0, sBl, tid);
        __syncthreads();
        half8 ah[4], al[4], bh[4], bl[4];
#pragma unroll
        for (int i = 0; i < 4; ++i) {
            int ra = wm + i * 16 + lr;
            ah[i] = *(const half8*)&sAh[ra * LP + lq * 8];
            al[i] = *(const half8*)&sAl[ra * LP + lq * 8];
            int rb = wn + i * 16 + lr;
            bh[i] = *(const half8*)&sBh[rb * LP + lq * 8];
            bl[i] = *(const half8*)&sBl[rb * LP + lq * 8];
        }
#pragma unroll
        for (int i = 0; i < 4; ++i)
#pragma unroll
            for (int j = 0; j < 4; ++j) {
                acc[i][j] = mfma16(ah[i], bh[j], acc[i][j]);
                acc[i][j] = mfma16(al[i], bh[j], acc[i][j]);
                acc[i][j] = mfma16(ah[i], bl[j], acc[i][j]);
            }
    }

    size_t sc_limit = (size_t)gridDim.z * S_ * S_;
#pragma unroll
    for (int j = 0; j < 4; ++j) {
        int t = nb + wn + j * 16 + lr;
#pragma unroll
        for (int i = 0; i < 4; ++i) {
            int s0 = mb + wm + i * 16 + lq * 4;
#pragma unroll
            for (int r = 0; r < 4; ++r) {
                size_t idx = ((size_t)blockIdx.z * S_ + s0 + r) * S_ + t;
                if (idx < sc_limit) SC[idx] = acc[i][j][r];
            }
        }
    }
}

// ---------------- softmax: SC fp32 -> AT fp16 ----------------
__global__ __launch_bounds__(256) void k_softmax(const float* __restrict__ SC,
                                                 u16* __restrict__ AT, int zbase) {
    int row = blockIdx.x;
    const float* src = SC + (size_t)row * S_;
    size_t drow = (size_t)zbase * S_ + row;
    u16* dst = AT + drow * S_;
    int tid = threadIdx.x;
    float v[8];
#pragma unroll
    for (int i = 0; i < 8; ++i) v[i] = src[tid + i * 256];
    float m = v[0];
#pragma unroll
    for (int i = 1; i < 8; ++i) m = fmaxf(m, v[i]);
    for (int off = 32; off > 0; off >>= 1) m = fmaxf(m, __shfl_down(m, off));
    __shared__ float redm[4], reds[4];
    if ((tid & 63) == 0) redm[tid >> 6] = m;
    __syncthreads();
    m = fmaxf(fmaxf(redm[0], redm[1]), fmaxf(redm[2], redm[3]));
    float s = 0.f;
#pragma unroll
    for (int i = 0; i < 8; ++i) { v[i] = __expf(v[i] - m); s += v[i]; }
    for (int off = 32; off > 0; off >>= 1) s += __shfl_down(s, off);
    if ((tid & 63) == 0) reds[tid >> 6] = s;
    __syncthreads();
    float inv = 1.0f / (reds[0] + reds[1] + reds[2] + reds[3]);
    if (drow * S_ + 2047 < AT_ELEMS) {
#pragma unroll
        for (int i = 0; i < 8; ++i) dst[tid + i * 256] = f2h(v[i] * inv);
    }
}

// ---------------- GEMM3: out = attn @ Vcat (plain fp16), planar epilogue ----------------
__global__ __launch_bounds__(256) void k_gemm3(
    const u16* __restrict__ AT, const u16* __restrict__ VT,
    float* __restrict__ out, int out_size, int full) {
    __shared__ __attribute__((aligned(16))) u16 sA[128 * LP], sB[128 * LP];
    int tid = threadIdx.x;
    int nb = blockIdx.x * 128, mb = blockIdx.y * 128, z = blockIdx.z;
    const u16* Abase = AT + (size_t)z * S_ * S_;
    const u16* Bbase = VT + (size_t)z * KC * S_;
    int lane = tid & 63, wave = tid >> 6;
    int wm = (wave >> 1) * 64, wn = (wave & 1) * 64;
    int lr = lane & 15, lq = lane >> 4;
    f32x4 acc[4][4] = {};

    for (int k0 = 0; k0 < S_; k0 += 32) {
        __syncthreads();
        stage_dma(Abase, S_, mb, k0, sA, tid);
        stage_dma(Bbase, S_, nb, k0, sB, tid);
        __syncthreads();
        half8 a[4], b[4];
#pragma unroll
        for (int i = 0; i < 4; ++i) {
            a[i] = *(const half8*)&sA[(wm + i * 16 + lr) * LP + lq * 8];
            b[i] = *(const half8*)&sB[(wn + i * 16 + lr) * LP + lq * 8];
        }
#pragma unroll
        for (int i = 0; i < 4; ++i)
#pragma unroll
            for (int j = 0; j < 4; ++j)
                acc[i][j] = mfma16(a[i], b[j], acc[i][j]);
    }

#pragma unroll
    for (int j = 0; j < 4; ++j) {
        int f = nb + wn + j * 16 + lr;
#pragma unroll
        for (int i = 0; i < 4; ++i) {
            int s0 = mb + wm + i * 16 + lq * 4;
#pragma unroll
            for (int r = 0; r < 4; ++r) {
                size_t base = ((size_t)z * S_ + s0 + r) * D_;
                if (f < D_) {
                    size_t o = base + f;
                    if (o < (size_t)out_size) out[o] = acc[i][j][r];
                } else if (full) {
                    size_t o = (size_t)RE_PLANE + base + (f - D_);
                    if (o < (size_t)out_size) out[o] = acc[i][j][r];
                }
            }
        }
    }
}

// ---------------- launch ----------------

extern "C" void kernel_launch(void* const* d_in, const int* in_sizes, int n_in,
                              void* d_out, int out_size, void* d_ws, size_t ws_size,
                              hipStream_t stream) {
    (void)in_sizes; (void)n_in;
    const float* xr  = (const float*)d_in[0];
    const float* xi  = (const float*)d_in[1];
    const float* Wqr = (const float*)d_in[2];
    const float* Wqi = (const float*)d_in[3];
    const float* bqr = (const float*)d_in[4];
    const float* bqi = (const float*)d_in[5];
    const float* Wkr = (const float*)d_in[6];
    const float* Wki = (const float*)d_in[7];
    const float* bkr = (const float*)d_in[8];
    const float* bki = (const float*)d_in[9];
    const float* Wvr = (const float*)d_in[10];
    const float* Wvi = (const float*)d_in[11];
    const float* bvr = (const float*)d_in[12];
    const float* bvi = (const float*)d_in[13];
    float* out = (float*)d_out;

    constexpr size_t SZ_X  = X_ELEMS * 2;          // 16 MiB each (Xh, Xl)
    constexpr size_t SZ_W  = W_ELEMS * 2;          // 6 MiB
    constexpr size_t SZ_BC = (size_t)N1 * 4;
    constexpr size_t SZ_QK = QK_ELEMS * 2;         // 16 MiB each (Qh,Ql,Kh,Kl)
    constexpr size_t SZ_VT = VT_ELEMS * 2;         // 16 MiB
    constexpr size_t SZ_SC_B = (size_t)S_ * S_ * 4;  // 16 MiB per batch

    char* p = (char*)d_ws;
    size_t off = 0;
    auto take = [&](size_t sz) {
        char* r = p + off;
        off += (sz + 255) & ~(size_t)255;
        return r;
    };
    u16*   Xh = (u16*)take(SZ_X);
    u16*   Xl = (u16*)take(SZ_X);
    u16*   Wh = (u16*)take(SZ_W);
    float* bc = (float*)take(SZ_BC);
    u16*   Qh = (u16*)take(SZ_QK);
    u16*   Ql = (u16*)take(SZ_QK);
    u16*   Kh = (u16*)take(SZ_QK);
    u16*   Kl = (u16*)take(SZ_QK);
    u16*   VT = (u16*)take(SZ_VT);
    u16*   AT = Xh;  // aliases Xh+Xl (32 MiB, dead after gemm1); no Qh overlap
    float* SC = (float*)(p + off);

    int nz = 0;
    if (ws_size > off) nz = (int)((ws_size - off) / SZ_SC_B);
    if (nz > B_) nz = B_;
    if (nz < 1) {
        k_diag<<<16, 256, 0, stream>>>(out, out_size, 1000.0f + (float)(ws_size >> 20));
        return;
    }

    int full = (out_size >= 2 * RE_PLANE) ? 1 : 0;

    k_prep<<<16384 + 12288 + 12, 256, 0, stream>>>(
        xr, xi, Wqr, Wqi, Wkr, Wki, Wvr, Wvi,
        bqr, bqi, bkr, bki, bvr, bvi, Xh, Xl, Wh, bc);
    k_gemm1<<<dim3(N1 / 256, M_TOT / 256), 512, 0, stream>>>(Xh, Xl, Wh, bc, Qh, Ql, Kh, Kl, VT);

    for (int z0 = 0; z0 < B_; z0 += nz) {
        int zc = (B_ - z0 < nz) ? (B_ - z0) : nz;
        k_gemm2<<<dim3(S_ / 128, S_ / 128, zc), 256, 0, stream>>>(Qh, Ql, Kh, Kl, SC, z0);
        k_softmax<<<zc * S_, 256, 0, stream>>>(SC, AT, z0);
    }
    k_gemm3<<<dim3(KC / 128, S_ / 128, B_), 256, 0, stream>>>(AT, VT, out, out_size, full);
}

// Round 4
// 412.157 us; speedup vs baseline: 1.0864x; 1.0603x over previous
//
#include <hip/hip_runtime.h>
#include <hip/hip_bf16.h>
#include <cstdint>
#include <cstddef>

// TeleportationAttention — R15: R14 resubmit with ONE de-risk change:
// raw asm s_barrier -> __builtin_amdgcn_s_barrier() (the form R12/R13 ran
// safely with; inline-asm barriers rely solely on "memory" clobber and
// hipcc's ordering around asm + register-only MFMA is not airtight).
// R14 design (re-audited this round: vmcnt ledger, WAR hazards, remap
// bijectivity, barrier uniformity all check out):
//   single-barrier pipelined windows {MFMA(q); ds_reads(q+1); stage; [VMW];
//   bar} -- one barrier/phase (4/tile vs 8), LDS read service overlaps
//   sibling-wave MFMA; Q/K blocks dispatch before half-length V blocks.
// Accumulation order unchanged -> absmax must stay 0.1289 (change = race).
// gemm2/softmax/gemm3/prep identical to R13.

typedef unsigned short u16;
typedef __attribute__((ext_vector_type(8))) _Float16 half8;
typedef __attribute__((ext_vector_type(4))) float f32x4;

#define B_    4
#define S_    2048
#define D_    512
#define M_TOT (B_ * S_)   // 8192
#define KC    (2 * D_)    // 1024
#define N1    (6 * D_)    // 3072
#define LP    32          // packed pitch for gemm2/gemm3 LDS
#define RE_PLANE 4194304  // B*S*D

#define X_ELEMS  ((size_t)M_TOT * KC)
#define W_ELEMS  ((size_t)N1 * KC)
#define QK_ELEMS ((size_t)M_TOT * KC)
#define VT_ELEMS ((size_t)B_ * KC * S_)
#define AT_ELEMS ((size_t)M_TOT * S_)

__device__ __forceinline__ u16 f2h(float f) {
    _Float16 h = (_Float16)f;              // RNE
    return __builtin_bit_cast(u16, h);
}
__device__ __forceinline__ float h2f(u16 b) {
    return (float)__builtin_bit_cast(_Float16, b);
}

__device__ __forceinline__ f32x4 mfma16(half8 a, half8 b, f32x4 c) {
    return __builtin_amdgcn_mfma_f32_16x16x32_f16(a, b, c, 0, 0, 0);
}

// async global->LDS, 16B per lane.
__device__ __forceinline__ void dma16(const u16* g, u16* l) {
    __builtin_amdgcn_global_load_lds(
        (const __attribute__((address_space(1))) unsigned int*)g,
        (__attribute__((address_space(3))) unsigned int*)l,
        16, 0, 0);
}

// ---- gemm2/gemm3 staging (unchanged): [128 x 32] tile into packed LDS ----
__device__ __forceinline__ void stage_dma(const u16* __restrict__ src, int ld,
                                          int rowbase, int kbase,
                                          u16* __restrict__ dst, int tid) {
#pragma unroll
    for (int i = 0; i < 2; ++i) {
        int c = tid + 256 * i;          // 0..511
        int row = c >> 2, q = c & 3;    // 4 x 16B per row
        dma16(src + (size_t)(rowbase + row) * ld + kbase + q * 8, dst + c * 8);
    }
}

// ---- gemm1 staging: one k-half plane = 256 rows x 32 k (16 KiB), stored as
// 128 lines of 128B (rows 2L,2L+1), swizzled byte^=((byte>>9)&1)<<5.
// global_load_lds writes LDS linearly -> fetch the inverse-swizzled source
// chunk. 512 threads x 2 x 16B = 16 KiB. ld fixed = KC.
__device__ __forceinline__ void stage_half(u16* __restrict__ plane,
                                           const u16* __restrict__ src,
                                           int rowbase, int kcol, int tid) {
#pragma unroll
    for (int i = 0; i < 2; ++i) {
        int c = tid + (i << 9);                 // physical 16B chunk [0,1024)
        int c2 = c ^ (((c >> 5) & 1) << 1);     // logical chunk (involution)
        int row = ((c2 >> 3) << 1) | ((c2 >> 2) & 1);
        int ks = c2 & 3;
        dma16(src + (size_t)(rowbase + row) * KC + (kcol + ks * 8),
              plane + c * 8);
    }
}

#define VMW(N) asm volatile("s_waitcnt vmcnt(" #N ")" ::: "memory")
#define BAR()  __builtin_amdgcn_s_barrier()

// ---------------- diagnostic fallback ----------------
__global__ void k_diag(float* __restrict__ out, int out_size, float val) {
    int i = blockIdx.x * 256 + threadIdx.x;
    if (i < out_size && i < 4096) out[i] = val;
}

// ---------------- merged prep: fp32 -> fp16 (X split, W single, bias) ----------------
__global__ void k_prep(const float* __restrict__ xr, const float* __restrict__ xi,
                       const float* __restrict__ Wqr, const float* __restrict__ Wqi,
                       const float* __restrict__ Wkr, const float* __restrict__ Wki,
                       const float* __restrict__ Wvr, const float* __restrict__ Wvi,
                       const float* __restrict__ bqr, const float* __restrict__ bqi,
                       const float* __restrict__ bkr, const float* __restrict__ bki,
                       const float* __restrict__ bvr, const float* __restrict__ bvi,
                       u16* __restrict__ Xh, u16* __restrict__ Xl,
                       u16* __restrict__ Wh, float* __restrict__ bc) {
    int gb = blockIdx.x;
    int tid = threadIdx.x;
    if (gb < 16384) {
        int id = gb * 256 + tid;                 // [0, 4194304)
        int m = id >> 9, d = id & 511;
        size_t o = (size_t)m * KC + d;
        if (o + D_ >= X_ELEMS) return;
        float vr = xr[id], vi = xi[id];
        u16 h;
        h = f2h(vr); Xh[o] = h;        Xl[o] = f2h(vr - h2f(h));
        h = f2h(vi); Xh[o + D_] = h;   Xl[o + D_] = f2h(vi - h2f(h));
    } else if (gb < 16384 + 12288) {
        int id = (gb - 16384) * 256 + tid;       // [0, 3145728)
        int n = id >> 10, k = id & 1023;
        int q = n >> 9, e = n & 511;
        int half = k >> 9, d = k & 511;
        const float* Wre = (q < 2) ? Wqr : ((q < 4) ? Wkr : Wvr);
        const float* Wim = (q < 2) ? Wqi : ((q < 4) ? Wki : Wvi);
        size_t src = (size_t)e * D_ + d;
        float v;
        if ((q & 1) == 0) v = half ? -Wim[src] : Wre[src];
        else              v = half ?  Wre[src] : Wim[src];
        if ((size_t)id < W_ELEMS) Wh[id] = f2h(v);
    } else {
        int id = (gb - 16384 - 12288) * 256 + tid;  // [0, 3072)
        if (id >= N1) return;
        int q = id >> 9, e = id & 511;
        const float* src = (q == 0) ? bqr : (q == 1) ? bqi : (q == 2) ? bkr
                         : (q == 3) ? bki : (q == 4) ? bvr : bvi;
        bc[id] = src[e];
    }
}

// ---------------- GEMM1: single-barrier pipelined windows ----------------
// Plane map: buf p (0/1): A-k0 = (p<<2)|0, A-k1 = (p<<2)|1,
//                         B-k0 = (p<<2)|2, B-k1 = (p<<2)|3.
// Window q (one barrier each):
//   q0: MFMA(aA,bA,mg0@k0); read aB<-A(t,k0)mg1;        stage A(t+1,k1); VMW(6)
//   q1: MFMA(aB,bA,mg1@k0); read bB<-B(t,k1), aA<-A(t,k1)mg0; stage B(t+1,k1)
//   q2: MFMA(aA,bB,mg0@k1); read aB<-A(t,k1)mg1;        stage A(t+2,k0); VMW(6)
//   q3: MFMA(aB,bB,mg1@k1); read bA<-B(t+1,k0), aA<-A(t+1,k0)mg0; stage B(t+2,k0)
// Hazards: each plane's last read is consumed by an MFMA (lgkmcnt-enforced)
// before the barrier preceding the overwriting DMA issue; VMW(6)@q0 publishes
// k1 planes for q1's reads, VMW(6)@q2 publishes next tile's k0 for q3's reads.

#define RDA(d, pl, mg)                                                        \
  { const u16* _pa = &lds[pl][0];                                             \
    _Pragma("unroll")                                                         \
    for (int _i = 0; _i < 4; ++_i)                                            \
      d[_i] = *(const half8*)(_pa + aoffs + ((mg) * 4 + _i) * 512); }
#define RDB(d, pl)                                                            \
  { const u16* _pb = &lds[pl][0];                                             \
    _Pragma("unroll")                                                         \
    for (int _i = 0; _i < 4; ++_i)                                            \
      d[_i] = *(const half8*)(_pb + boffs + _i * 512); }
#define MF16(av, bv, mg)                                                      \
  { __builtin_amdgcn_s_setprio(1);                                            \
    _Pragma("unroll")                                                         \
    for (int _j = 0; _j < 4; ++_j) {                                          \
      _Pragma("unroll")                                                       \
      for (int _i = 0; _i < 4; ++_i)                                          \
        acc[(mg) * 4 + _i][_j] =                                              \
            mfma16(av[_i], bv[_j], acc[(mg) * 4 + _i][_j]);                   \
    }                                                                         \
    __builtin_amdgcn_s_setprio(0); }

#define W0(P, STG, WT) { MF16(aA, bA, 0); RDA(aB, ((P) << 2) | 0, 1); STG; WT; BAR(); }
#define W1(P, STG)     { MF16(aB, bA, 1); RDB(bB, ((P) << 2) | 3); RDA(aA, ((P) << 2) | 1, 0); STG; BAR(); }
#define W2(P, STG, WT) { MF16(aA, bB, 0); RDA(aB, ((P) << 2) | 1, 1); STG; WT; BAR(); }
#define W3(P, STG)     { MF16(aB, bB, 1); RDB(bA, (((P) ^ 1) << 2) | 2); RDA(aA, (((P) ^ 1) << 2) | 0, 0); STG; BAR(); }
#define W3L()          { MF16(aB, bB, 1); }
#define NOP_ ((void)0)

__global__ __launch_bounds__(512, 2) void k_gemm1(
    const u16* __restrict__ Xh, const u16* __restrict__ Xl,
    const u16* __restrict__ Wh,
    const float* __restrict__ bc,
    u16* __restrict__ Qh, u16* __restrict__ Ql,
    u16* __restrict__ Kh, u16* __restrict__ Kl,
    u16* __restrict__ VT) {
    __shared__ __attribute__((aligned(16))) u16 lds[8][8192];
    int tid = threadIdx.x;

    // Q/K blocks (NT=32) first, V blocks (NT=16) last; XCD-chunked within each.
    int L = blockIdx.y * 12 + blockIdx.x;      // launch order, x fastest
    int bx, by;
    if (L < 256) {                             // Q/K: 8 n-tiles x 32 m-tiles
        int q = (L & 7) * 32 + (L >> 3);
        bx = q & 7; by = q >> 3;
    } else {                                   // V: 4 n-tiles x 32 m-tiles
        int v = L - 256;
        int vv = (v & 7) * 16 + (v >> 3);
        bx = 8 + (vv & 3); by = vv >> 2;
    }
    int nb = bx * 256, mb = by * 256;
    int g = bx >> 2;                 // 0:Q 1:K 2:V (block-uniform)
    bool vblk = (g == 2);
    int NT = vblk ? 16 : 32;         // extended-K tiles of 64

    int lane = tid & 63, wave = tid >> 6;
    int wm = (wave >> 2) * 128, wn = (wave & 3) * 64;   // 2x4 waves
    int lr = lane & 15, lq = lane >> 4;
    // swizzled read offset: phys chunk = (row*4 + lq) ^ (2 if row&8); row&8 == lr&8
    int lqs8 = (lq ^ (((lr >> 3) & 1) << 1)) * 8;
    int aoffs = (wm + lr) * 32 + lqs8;
    int boffs = (wn + lr) * 32 + lqs8;

    f32x4 acc[8][4] = {};
    half8 aA[4], aB[4], bA[4], bB[4];

    // prologue: tile 0 (both k-halves) + tile 1 k0 => 12 loads in flight
    stage_half(&lds[0][0], Xh, mb, 0, tid);    // A(0,k0)
    stage_half(&lds[2][0], Wh, nb, 0, tid);    // B(0,k0)
    stage_half(&lds[1][0], Xh, mb, 32, tid);   // A(0,k1)
    stage_half(&lds[3][0], Wh, nb, 32, tid);   // B(0,k1)
    stage_half(&lds[4][0], Xh, mb, 64, tid);   // A(1,k0)
    stage_half(&lds[6][0], Wh, nb, 64, tid);   // B(1,k0)
    VMW(8);                                    // A/B(0,k0) landed
    BAR();
    RDB(bA, 2);                                // B(0,k0)
    RDA(aA, 0, 0);                             // A(0,k0) mg0

    for (int t = 0; t < NT - 2; ++t) {
        const int p = t & 1;
        const u16* s1 = (!vblk && (t + 1) >= 16) ? Xl : Xh;
        const int k1 = (((t + 1) & 15) << 6) + 32;
        const u16* s2 = (!vblk && (t + 2) >= 16) ? Xl : Xh;
        const int k2 = ((t + 2) & 15) << 6;
        W0(p, stage_half(&lds[((p ^ 1) << 2) | 1][0], s1, mb, k1, tid), VMW(6));
        W1(p, stage_half(&lds[((p ^ 1) << 2) | 3][0], Wh, nb, k1, tid));
        W2(p, stage_half(&lds[(p << 2) | 0][0], s2, mb, k2, tid), VMW(6));
        W3(p, stage_half(&lds[(p << 2) | 2][0], Wh, nb, k2, tid));
    }
    {   // t = NT-2 (p = 0): only tile NT-1's k1 left to stage
        const u16* s1 = vblk ? Xh : Xl;        // tile NT-1: seg1 for Q/K
        const int k1 = (((NT - 1) & 15) << 6) + 32;
        W0(0, stage_half(&lds[(1 << 2) | 1][0], s1, mb, k1, tid), VMW(6));
        W1(0, stage_half(&lds[(1 << 2) | 3][0], Wh, nb, k1, tid));
        W2(0, NOP_, VMW(4));                   // A/B(NT-1,k0) landed
        W3(0, NOP_);                           // reads A/B(NT-1,k0)
    }
    {   // t = NT-1 (p = 1): drain
        W0(1, NOP_, VMW(0));                   // A/B(NT-1,k1) landed
        W1(1, NOP_);
        W2(1, NOP_, NOP_);
        W3L();
    }

    // epilogue (unchanged math)
#pragma unroll
    for (int j = 0; j < 4; ++j) {
        int n_g = nb + wn + j * 16 + lr;
        float bias = bc[n_g];
        int c = n_g & 1023;
#pragma unroll
        for (int i = 0; i < 8; ++i) {
            int m0 = mb + wm + i * 16 + lq * 4;
            if (vblk) {
                int bidx = m0 >> 11, s0 = m0 & 2047;
                u16 pk[4];
#pragma unroll
                for (int r = 0; r < 4; ++r) pk[r] = f2h(acc[i][j][r] + bias);
                size_t idx = ((size_t)(bidx * KC + c)) * S_ + s0;
                if (idx + 3 < VT_ELEMS)
                    *(ushort4*)&VT[idx] = make_ushort4(pk[0], pk[1], pk[2], pk[3]);
            } else {
                u16* dh = g ? Kh : Qh;
                u16* dl = g ? Kl : Ql;
#pragma unroll
                for (int r = 0; r < 4; ++r) {
                    float v = acc[i][j][r] + bias;
                    u16 h = f2h(v);
                    size_t idx = (size_t)(m0 + r) * KC + c;
                    if (idx < QK_ELEMS) {
                        dh[idx] = h;
                        dl[idx] = f2h(v - h2f(h));
                    }
                }
            }
        }
    }
}

// ---------------- GEMM2: scores (3-term: QhKh + QlKh + QhKl) ----------------
__global__ __launch_bounds__(256) void k_gemm2(
    const u16* __restrict__ Qh, const u16* __restrict__ Ql,
    const u16* __restrict__ Kh, const u16* __restrict__ Kl,
    float* __restrict__ SC, int zbase) {
    __shared__ __attribute__((aligned(16))) u16 sAh[128 * LP], sAl[128 * LP],
                                                sBh[128 * LP], sBl[128 * LP];
    int tid = threadIdx.x;
    int nb = blockIdx.x * 128, mb = blockIdx.y * 128;
    int z = zbase + blockIdx.z;
    const u16* Ah = Qh + (size_t)z * S_ * KC;
    const u16* Al = Ql + (size_t)z * S_ * KC;
    const u16* Bh = Kh + (size_t)z * S_ * KC;
    const u16* Bl = Kl + (size_t)z * S_ * KC;
    int lane = tid & 63, wave = tid >> 6;
    int wm = (wave >> 1) * 64, wn = (wave & 1) * 64;
    int lr = lane & 15, lq = lane >> 4;
    f32x4 acc[4][4] = {};

    for (int k0 = 0; k0 < KC; k0 += 32) {
        __syncthreads();
        stage_dma(Ah, KC, mb, k0, sAh, tid);
        stage_dma(Al, KC, mb, k0, sAl, tid);
        stage_dma(Bh, KC, nb, k0, sBh, tid);
        stage_dma(Bl, KC, nb, k0, sBl, tid);
        __syncthreads();
        half8 ah[4], al[4], bh[4], bl[4];
#pragma unroll
        for (int i = 0; i < 4; ++i) {
            int ra = wm + i * 16 + lr;
            ah[i] = *(const half8*)&sAh[ra * LP + lq * 8];
            al[i] = *(const half8*)&sAl[ra * LP + lq * 8];
            int rb = wn + i * 16 + lr;
            bh[i] = *(const half8*)&sBh[rb * LP + lq * 8];
            bl[i] = *(const half8*)&sBl[rb * LP + lq * 8];
        }
#pragma unroll
        for (int i = 0; i < 4; ++i)
#pragma unroll
            for (int j = 0; j < 4; ++j) {
                acc[i][j] = mfma16(ah[i], bh[j], acc[i][j]);
                acc[i][j] = mfma16(al[i], bh[j], acc[i][j]);
                acc[i][j] = mfma16(ah[i], bl[j], acc[i][j]);
            }
    }

    size_t sc_limit = (size_t)gridDim.z * S_ * S_;
#pragma unroll
    for (int j = 0; j < 4; ++j) {
        int t = nb + wn + j * 16 + lr;
#pragma unroll
        for (int i = 0; i < 4; ++i) {
            int s0 = mb + wm + i * 16 + lq * 4;
#pragma unroll
            for (int r = 0; r < 4; ++r) {
                size_t idx = ((size_t)blockIdx.z * S_ + s0 + r) * S_ + t;
                if (idx < sc_limit) SC[idx] = acc[i][j][r];
            }
        }
    }
}

// ---------------- softmax: SC fp32 -> AT fp16 ----------------
__global__ __launch_bounds__(256) void k_softmax(const float* __restrict__ SC,
                                                 u16* __restrict__ AT, int zbase) {
    int row = blockIdx.x;
    const float* src = SC + (size_t)row * S_;
    size_t drow = (size_t)zbase * S_ + row;
    u16* dst = AT + drow * S_;
    int tid = threadIdx.x;
    float v[8];
#pragma unroll
    for (int i = 0; i < 8; ++i) v[i] = src[tid + i * 256];
    float m = v[0];
#pragma unroll
    for (int i = 1; i < 8; ++i) m = fmaxf(m, v[i]);
    for (int off = 32; off > 0; off >>= 1) m = fmaxf(m, __shfl_down(m, off));
    __shared__ float redm[4], reds[4];
    if ((tid & 63) == 0) redm[tid >> 6] = m;
    __syncthreads();
    m = fmaxf(fmaxf(redm[0], redm[1]), fmaxf(redm[2], redm[3]));
    float s = 0.f;
#pragma unroll
    for (int i = 0; i < 8; ++i) { v[i] = __expf(v[i] - m); s += v[i]; }
    for (int off = 32; off > 0; off >>= 1) s += __shfl_down(s, off);
    if ((tid & 63) == 0) reds[tid >> 6] = s;
    __syncthreads();
    float inv = 1.0f / (reds[0] + reds[1] + reds[2] + reds[3]);
    if (drow * S_ + 2047 < AT_ELEMS) {
#pragma unroll
        for (int i = 0; i < 8; ++i) dst[tid + i * 256] = f2h(v[i] * inv);
    }
}

// ---------------- GEMM3: out = attn @ Vcat (plain fp16), planar epilogue ----------------
__global__ __launch_bounds__(256) void k_gemm3(
    const u16* __restrict__ AT, const u16* __restrict__ VT,
    float* __restrict__ out, int out_size, int full) {
    __shared__ __attribute__((aligned(16))) u16 sA[128 * LP], sB[128 * LP];
    int tid = threadIdx.x;
    int nb = blockIdx.x * 128, mb = blockIdx.y * 128, z = blockIdx.z;
    const u16* Abase = AT + (size_t)z * S_ * S_;
    const u16* Bbase = VT + (size_t)z * KC * S_;
    int lane = tid & 63, wave = tid >> 6;
    int wm = (wave >> 1) * 64, wn = (wave & 1) * 64;
    int lr = lane & 15, lq = lane >> 4;
    f32x4 acc[4][4] = {};

    for (int k0 = 0; k0 < S_; k0 += 32) {
        __syncthreads();
        stage_dma(Abase, S_, mb, k0, sA, tid);
        stage_dma(Bbase, S_, nb, k0, sB, tid);
        __syncthreads();
        half8 a[4], b[4];
#pragma unroll
        for (int i = 0; i < 4; ++i) {
            a[i] = *(const half8*)&sA[(wm + i * 16 + lr) * LP + lq * 8];
            b[i] = *(const half8*)&sB[(wn + i * 16 + lr) * LP + lq * 8];
        }
#pragma unroll
        for (int i = 0; i < 4; ++i)
#pragma unroll
            for (int j = 0; j < 4; ++j)
                acc[i][j] = mfma16(a[i], b[j], acc[i][j]);
    }

#pragma unroll
    for (int j = 0; j < 4; ++j) {
        int f = nb + wn + j * 16 + lr;
#pragma unroll
        for (int i = 0; i < 4; ++i) {
            int s0 = mb + wm + i * 16 + lq * 4;
#pragma unroll
            for (int r = 0; r < 4; ++r) {
                size_t base = ((size_t)z * S_ + s0 + r) * D_;
                if (f < D_) {
                    size_t o = base + f;
                    if (o < (size_t)out_size) out[o] = acc[i][j][r];
                } else if (full) {
                    size_t o = (size_t)RE_PLANE + base + (f - D_);
                    if (o < (size_t)out_size) out[o] = acc[i][j][r];
                }
            }
        }
    }
}

// ---------------- launch ----------------

extern "C" void kernel_launch(void* const* d_in, const int* in_sizes, int n_in,
                              void* d_out, int out_size, void* d_ws, size_t ws_size,
                              hipStream_t stream) {
    (void)in_sizes; (void)n_in;
    const float* xr  = (const float*)d_in[0];
    const float* xi  = (const float*)d_in[1];
    const float* Wqr = (const float*)d_in[2];
    const float* Wqi = (const float*)d_in[3];
    const float* bqr = (const float*)d_in[4];
    const float* bqi = (const float*)d_in[5];
    const float* Wkr = (const float*)d_in[6];
    const float* Wki = (const float*)d_in[7];
    const float* bkr = (const float*)d_in[8];
    const float* bki = (const float*)d_in[9];
    const float* Wvr = (const float*)d_in[10];
    const float* Wvi = (const float*)d_in[11];
    const float* bvr = (const float*)d_in[12];
    const float* bvi = (const float*)d_in[13];
    float* out = (float*)d_out;

    constexpr size_t SZ_X  = X_ELEMS * 2;          // 16 MiB each (Xh, Xl)
    constexpr size_t SZ_W  = W_ELEMS * 2;          // 6 MiB
    constexpr size_t SZ_BC = (size_t)N1 * 4;
    constexpr size_t SZ_QK = QK_ELEMS * 2;         // 16 MiB each (Qh,Ql,Kh,Kl)
    constexpr size_t SZ_VT = VT_ELEMS * 2;         // 16 MiB
    constexpr size_t SZ_SC_B = (size_t)S_ * S_ * 4;  // 16 MiB per batch

    char* p = (char*)d_ws;
    size_t off = 0;
    auto take = [&](size_t sz) {
        char* r = p + off;
        off += (sz + 255) & ~(size_t)255;
        return r;
    };
    u16*   Xh = (u16*)take(SZ_X);
    u16*   Xl = (u16*)take(SZ_X);
    u16*   Wh = (u16*)take(SZ_W);
    float* bc = (float*)take(SZ_BC);
    u16*   Qh = (u16*)take(SZ_QK);
    u16*   Ql = (u16*)take(SZ_QK);
    u16*   Kh = (u16*)take(SZ_QK);
    u16*   Kl = (u16*)take(SZ_QK);
    u16*   VT = (u16*)take(SZ_VT);
    u16*   AT = Xh;  // aliases Xh+Xl (32 MiB, dead after gemm1); no Qh overlap
    float* SC = (float*)(p + off);

    int nz = 0;
    if (ws_size > off) nz = (int)((ws_size - off) / SZ_SC_B);
    if (nz > B_) nz = B_;
    if (nz < 1) {
        k_diag<<<16, 256, 0, stream>>>(out, out_size, 1000.0f + (float)(ws_size >> 20));
        return;
    }

    int full = (out_size >= 2 * RE_PLANE) ? 1 : 0;

    k_prep<<<16384 + 12288 + 12, 256, 0, stream>>>(
        xr, xi, Wqr, Wqi, Wkr, Wki, Wvr, Wvi,
        bqr, bqi, bkr, bki, bvr, bvi, Xh, Xl, Wh, bc);
    k_gemm1<<<dim3(12, 32), 512, 0, stream>>>(Xh, Xl, Wh, bc, Qh, Ql, Kh, Kl, VT);

    for (int z0 = 0; z0 < B_; z0 += nz) {
        int zc = (B_ - z0 < nz) ? (B_ - z0) : nz;
        k_gemm2<<<dim3(S_ / 128, S_ / 128, zc), 256, 0, stream>>>(Qh, Ql, Kh, Kl, SC, z0);
        k_softmax<<<zc * S_, 256, 0, stream>>>(SC, AT, z0);
    }
    k_gemm3<<<dim3(KC / 128, S_ / 128, B_), 256, 0, stream>>>(AT, VT, out, out_size, full);
}

// Round 5
// 390.430 us; speedup vs baseline: 1.1468x; 1.0556x over previous
//
#include <hip/hip_runtime.h>
#include <hip/hip_bf16.h>
#include <cstdint>
#include <cstddef>

// TeleportationAttention — R16: R15 (412us) + k_gemm2 ported to the proven
// single-barrier-window 256^2 structure (R15's k_gemm1 schedule, verified
// twice: absmax bit-stable, bank-conflicts 0, ~704 TF effective).
//  * gemm2 extended-K: 3-term (QhKh + QlKh + QhKl) = one plain GEMM over
//    K'=3072, NT=48; per-segment A-src {Qh,Ql,Qh}, B-src {Kh,Kh,Kl}.
//  * grid (8,8,4) = 256 blocks = 1 block/CU exactly, zero tail (beats
//    gemm1's 1.5 rounds). Natural order gives per-XCD K-panel affinity.
//  * fallback to old 128^2 gemm2 when zc<4 (underfill guard).
//  * K-term accumulation reordered (full-K per term) -> fp32 reassociation
//    only; absmax may wiggle slightly (expected, not a race flag).
// gemm1/softmax/gemm3/prep identical to R15.

typedef unsigned short u16;
typedef __attribute__((ext_vector_type(8))) _Float16 half8;
typedef __attribute__((ext_vector_type(4))) float f32x4;

#define B_    4
#define S_    2048
#define D_    512
#define M_TOT (B_ * S_)   // 8192
#define KC    (2 * D_)    // 1024
#define N1    (6 * D_)    // 3072
#define LP    32          // packed pitch for legacy gemm2/gemm3 LDS
#define RE_PLANE 4194304  // B*S*D

#define X_ELEMS  ((size_t)M_TOT * KC)
#define W_ELEMS  ((size_t)N1 * KC)
#define QK_ELEMS ((size_t)M_TOT * KC)
#define VT_ELEMS ((size_t)B_ * KC * S_)
#define AT_ELEMS ((size_t)M_TOT * S_)

__device__ __forceinline__ u16 f2h(float f) {
    _Float16 h = (_Float16)f;              // RNE
    return __builtin_bit_cast(u16, h);
}
__device__ __forceinline__ float h2f(u16 b) {
    return (float)__builtin_bit_cast(_Float16, b);
}

__device__ __forceinline__ f32x4 mfma16(half8 a, half8 b, f32x4 c) {
    return __builtin_amdgcn_mfma_f32_16x16x32_f16(a, b, c, 0, 0, 0);
}

// async global->LDS, 16B per lane.
__device__ __forceinline__ void dma16(const u16* g, u16* l) {
    __builtin_amdgcn_global_load_lds(
        (const __attribute__((address_space(1))) unsigned int*)g,
        (__attribute__((address_space(3))) unsigned int*)l,
        16, 0, 0);
}

// ---- legacy staging (gemm2 fallback / gemm3): [128 x 32] tile, packed ----
__device__ __forceinline__ void stage_dma(const u16* __restrict__ src, int ld,
                                          int rowbase, int kbase,
                                          u16* __restrict__ dst, int tid) {
#pragma unroll
    for (int i = 0; i < 2; ++i) {
        int c = tid + 256 * i;          // 0..511
        int row = c >> 2, q = c & 3;    // 4 x 16B per row
        dma16(src + (size_t)(rowbase + row) * ld + kbase + q * 8, dst + c * 8);
    }
}

// ---- 256^2 staging: one k-half plane = 256 rows x 32 k (16 KiB), stored as
// 128 lines of 128B (rows 2L,2L+1), swizzled byte^=((byte>>9)&1)<<5.
// global_load_lds writes LDS linearly -> fetch the inverse-swizzled source
// chunk. 512 threads x 2 x 16B = 16 KiB. ld fixed = KC.
__device__ __forceinline__ void stage_half(u16* __restrict__ plane,
                                           const u16* __restrict__ src,
                                           int rowbase, int kcol, int tid) {
#pragma unroll
    for (int i = 0; i < 2; ++i) {
        int c = tid + (i << 9);                 // physical 16B chunk [0,1024)
        int c2 = c ^ (((c >> 5) & 1) << 1);     // logical chunk (involution)
        int row = ((c2 >> 3) << 1) | ((c2 >> 2) & 1);
        int ks = c2 & 3;
        dma16(src + (size_t)(rowbase + row) * KC + (kcol + ks * 8),
              plane + c * 8);
    }
}

#define VMW(N) asm volatile("s_waitcnt vmcnt(" #N ")" ::: "memory")
#define BAR()  __builtin_amdgcn_s_barrier()

// ---------------- diagnostic fallback ----------------
__global__ void k_diag(float* __restrict__ out, int out_size, float val) {
    int i = blockIdx.x * 256 + threadIdx.x;
    if (i < out_size && i < 4096) out[i] = val;
}

// ---------------- merged prep: fp32 -> fp16 (X split, W single, bias) ----------------
__global__ void k_prep(const float* __restrict__ xr, const float* __restrict__ xi,
                       const float* __restrict__ Wqr, const float* __restrict__ Wqi,
                       const float* __restrict__ Wkr, const float* __restrict__ Wki,
                       const float* __restrict__ Wvr, const float* __restrict__ Wvi,
                       const float* __restrict__ bqr, const float* __restrict__ bqi,
                       const float* __restrict__ bkr, const float* __restrict__ bki,
                       const float* __restrict__ bvr, const float* __restrict__ bvi,
                       u16* __restrict__ Xh, u16* __restrict__ Xl,
                       u16* __restrict__ Wh, float* __restrict__ bc) {
    int gb = blockIdx.x;
    int tid = threadIdx.x;
    if (gb < 16384) {
        int id = gb * 256 + tid;                 // [0, 4194304)
        int m = id >> 9, d = id & 511;
        size_t o = (size_t)m * KC + d;
        if (o + D_ >= X_ELEMS) return;
        float vr = xr[id], vi = xi[id];
        u16 h;
        h = f2h(vr); Xh[o] = h;        Xl[o] = f2h(vr - h2f(h));
        h = f2h(vi); Xh[o + D_] = h;   Xl[o + D_] = f2h(vi - h2f(h));
    } else if (gb < 16384 + 12288) {
        int id = (gb - 16384) * 256 + tid;       // [0, 3145728)
        int n = id >> 10, k = id & 1023;
        int q = n >> 9, e = n & 511;
        int half = k >> 9, d = k & 511;
        const float* Wre = (q < 2) ? Wqr : ((q < 4) ? Wkr : Wvr);
        const float* Wim = (q < 2) ? Wqi : ((q < 4) ? Wki : Wvi);
        size_t src = (size_t)e * D_ + d;
        float v;
        if ((q & 1) == 0) v = half ? -Wim[src] : Wre[src];
        else              v = half ?  Wre[src] : Wim[src];
        if ((size_t)id < W_ELEMS) Wh[id] = f2h(v);
    } else {
        int id = (gb - 16384 - 12288) * 256 + tid;  // [0, 3072)
        if (id >= N1) return;
        int q = id >> 9, e = id & 511;
        const float* src = (q == 0) ? bqr : (q == 1) ? bqi : (q == 2) ? bkr
                         : (q == 3) ? bki : (q == 4) ? bvr : bvi;
        bc[id] = src[e];
    }
}

// ---------------- shared 256^2 single-barrier window machinery ----------------
// Plane map: buf p (0/1): A-k0 = (p<<2)|0, A-k1 = (p<<2)|1,
//                         B-k0 = (p<<2)|2, B-k1 = (p<<2)|3.
// Window q (one barrier each):
//   q0: MFMA(aA,bA,mg0@k0); read aB<-A(t,k0)mg1;        stage A(t+1,k1); VMW(6)
//   q1: MFMA(aB,bA,mg1@k0); read bB<-B(t,k1), aA<-A(t,k1)mg0; stage B(t+1,k1)
//   q2: MFMA(aA,bB,mg0@k1); read aB<-A(t,k1)mg1;        stage A(t+2,k0); VMW(6)
//   q3: MFMA(aB,bB,mg1@k1); read bA<-B(t+1,k0), aA<-A(t+1,k0)mg0; stage B(t+2,k0)

#define RDA(d, pl, mg)                                                        \
  { const u16* _pa = &lds[pl][0];                                             \
    _Pragma("unroll")                                                         \
    for (int _i = 0; _i < 4; ++_i)                                            \
      d[_i] = *(const half8*)(_pa + aoffs + ((mg) * 4 + _i) * 512); }
#define RDB(d, pl)                                                            \
  { const u16* _pb = &lds[pl][0];                                             \
    _Pragma("unroll")                                                         \
    for (int _i = 0; _i < 4; ++_i)                                            \
      d[_i] = *(const half8*)(_pb + boffs + _i * 512); }
#define MF16(av, bv, mg)                                                      \
  { __builtin_amdgcn_s_setprio(1);                                            \
    _Pragma("unroll")                                                         \
    for (int _j = 0; _j < 4; ++_j) {                                          \
      _Pragma("unroll")                                                       \
      for (int _i = 0; _i < 4; ++_i)                                          \
        acc[(mg) * 4 + _i][_j] =                                              \
            mfma16(av[_i], bv[_j], acc[(mg) * 4 + _i][_j]);                   \
    }                                                                         \
    __builtin_amdgcn_s_setprio(0); }

#define W0(P, STG, WT) { MF16(aA, bA, 0); RDA(aB, ((P) << 2) | 0, 1); STG; WT; BAR(); }
#define W1(P, STG)     { MF16(aB, bA, 1); RDB(bB, ((P) << 2) | 3); RDA(aA, ((P) << 2) | 1, 0); STG; BAR(); }
#define W2(P, STG, WT) { MF16(aA, bB, 0); RDA(aB, ((P) << 2) | 1, 1); STG; WT; BAR(); }
#define W3(P, STG)     { MF16(aB, bB, 1); RDB(bA, (((P) ^ 1) << 2) | 2); RDA(aA, (((P) ^ 1) << 2) | 0, 0); STG; BAR(); }
#define W3L()          { MF16(aB, bB, 1); }
#define NOP_ ((void)0)

// ---------------- GEMM1: projections (unchanged from R15) ----------------
__global__ __launch_bounds__(512, 2) void k_gemm1(
    const u16* __restrict__ Xh, const u16* __restrict__ Xl,
    const u16* __restrict__ Wh,
    const float* __restrict__ bc,
    u16* __restrict__ Qh, u16* __restrict__ Ql,
    u16* __restrict__ Kh, u16* __restrict__ Kl,
    u16* __restrict__ VT) {
    __shared__ __attribute__((aligned(16))) u16 lds[8][8192];
    int tid = threadIdx.x;

    // Q/K blocks (NT=32) first, V blocks (NT=16) last; XCD-chunked within each.
    int L = blockIdx.y * 12 + blockIdx.x;      // launch order, x fastest
    int bx, by;
    if (L < 256) {                             // Q/K: 8 n-tiles x 32 m-tiles
        int q = (L & 7) * 32 + (L >> 3);
        bx = q & 7; by = q >> 3;
    } else {                                   // V: 4 n-tiles x 32 m-tiles
        int v = L - 256;
        int vv = (v & 7) * 16 + (v >> 3);
        bx = 8 + (vv & 3); by = vv >> 2;
    }
    int nb = bx * 256, mb = by * 256;
    int g = bx >> 2;                 // 0:Q 1:K 2:V (block-uniform)
    bool vblk = (g == 2);
    int NT = vblk ? 16 : 32;         // extended-K tiles of 64

    int lane = tid & 63, wave = tid >> 6;
    int wm = (wave >> 2) * 128, wn = (wave & 3) * 64;   // 2x4 waves
    int lr = lane & 15, lq = lane >> 4;
    // swizzled read offset: phys chunk = (row*4 + lq) ^ (2 if row&8); row&8 == lr&8
    int lqs8 = (lq ^ (((lr >> 3) & 1) << 1)) * 8;
    int aoffs = (wm + lr) * 32 + lqs8;
    int boffs = (wn + lr) * 32 + lqs8;

    f32x4 acc[8][4] = {};
    half8 aA[4], aB[4], bA[4], bB[4];

    // prologue: tile 0 (both k-halves) + tile 1 k0 => 12 loads in flight
    stage_half(&lds[0][0], Xh, mb, 0, tid);    // A(0,k0)
    stage_half(&lds[2][0], Wh, nb, 0, tid);    // B(0,k0)
    stage_half(&lds[1][0], Xh, mb, 32, tid);   // A(0,k1)
    stage_half(&lds[3][0], Wh, nb, 32, tid);   // B(0,k1)
    stage_half(&lds[4][0], Xh, mb, 64, tid);   // A(1,k0)
    stage_half(&lds[6][0], Wh, nb, 64, tid);   // B(1,k0)
    VMW(8);                                    // A/B(0,k0) landed
    BAR();
    RDB(bA, 2);                                // B(0,k0)
    RDA(aA, 0, 0);                             // A(0,k0) mg0

    for (int t = 0; t < NT - 2; ++t) {
        const int p = t & 1;
        const u16* s1 = (!vblk && (t + 1) >= 16) ? Xl : Xh;
        const int k1 = (((t + 1) & 15) << 6) + 32;
        const u16* s2 = (!vblk && (t + 2) >= 16) ? Xl : Xh;
        const int k2 = ((t + 2) & 15) << 6;
        W0(p, stage_half(&lds[((p ^ 1) << 2) | 1][0], s1, mb, k1, tid), VMW(6));
        W1(p, stage_half(&lds[((p ^ 1) << 2) | 3][0], Wh, nb, k1, tid));
        W2(p, stage_half(&lds[(p << 2) | 0][0], s2, mb, k2, tid), VMW(6));
        W3(p, stage_half(&lds[(p << 2) | 2][0], Wh, nb, k2, tid));
    }
    {   // t = NT-2 (p = 0): only tile NT-1's k1 left to stage
        const u16* s1 = vblk ? Xh : Xl;        // tile NT-1: seg1 for Q/K
        const int k1 = (((NT - 1) & 15) << 6) + 32;
        W0(0, stage_half(&lds[(1 << 2) | 1][0], s1, mb, k1, tid), VMW(6));
        W1(0, stage_half(&lds[(1 << 2) | 3][0], Wh, nb, k1, tid));
        W2(0, NOP_, VMW(4));                   // A/B(NT-1,k0) landed
        W3(0, NOP_);                           // reads A/B(NT-1,k0)
    }
    {   // t = NT-1 (p = 1): drain
        W0(1, NOP_, VMW(0));                   // A/B(NT-1,k1) landed
        W1(1, NOP_);
        W2(1, NOP_, NOP_);
        W3L();
    }

    // epilogue (unchanged math)
#pragma unroll
    for (int j = 0; j < 4; ++j) {
        int n_g = nb + wn + j * 16 + lr;
        float bias = bc[n_g];
        int c = n_g & 1023;
#pragma unroll
        for (int i = 0; i < 8; ++i) {
            int m0 = mb + wm + i * 16 + lq * 4;
            if (vblk) {
                int bidx = m0 >> 11, s0 = m0 & 2047;
                u16 pk[4];
#pragma unroll
                for (int r = 0; r < 4; ++r) pk[r] = f2h(acc[i][j][r] + bias);
                size_t idx = ((size_t)(bidx * KC + c)) * S_ + s0;
                if (idx + 3 < VT_ELEMS)
                    *(ushort4*)&VT[idx] = make_ushort4(pk[0], pk[1], pk[2], pk[3]);
            } else {
                u16* dh = g ? Kh : Qh;
                u16* dl = g ? Kl : Ql;
#pragma unroll
                for (int r = 0; r < 4; ++r) {
                    float v = acc[i][j][r] + bias;
                    u16 h = f2h(v);
                    size_t idx = (size_t)(m0 + r) * KC + c;
                    if (idx < QK_ELEMS) {
                        dh[idx] = h;
                        dl[idx] = f2h(v - h2f(h));
                    }
                }
            }
        }
    }
}

// ---------------- GEMM2 (256^2 windows): scores via extended-K=3072 ----------------
// Segments (16 tiles of 64 each): seg0 = Qh·Kh, seg1 = Ql·Kh, seg2 = Qh·Kl.
__global__ __launch_bounds__(512, 2) void k_gemm2_256(
    const u16* __restrict__ Qh, const u16* __restrict__ Ql,
    const u16* __restrict__ Kh, const u16* __restrict__ Kl,
    float* __restrict__ SC, int zbase) {
    __shared__ __attribute__((aligned(16))) u16 lds[8][8192];
    int tid = threadIdx.x;
    int z = zbase + blockIdx.z;
    const u16* Aq = Qh + (size_t)z * S_ * KC;   // seg0/2 A
    const u16* Al = Ql + (size_t)z * S_ * KC;   // seg1   A
    const u16* Bh = Kh + (size_t)z * S_ * KC;   // seg0/1 B
    const u16* Bl = Kl + (size_t)z * S_ * KC;   // seg2   B
    int nb = blockIdx.x * 256, mb = blockIdx.y * 256;
    const int NT = 48;

    int lane = tid & 63, wave = tid >> 6;
    int wm = (wave >> 2) * 128, wn = (wave & 3) * 64;   // 2x4 waves
    int lr = lane & 15, lq = lane >> 4;
    int lqs8 = (lq ^ (((lr >> 3) & 1) << 1)) * 8;
    int aoffs = (wm + lr) * 32 + lqs8;
    int boffs = (wn + lr) * 32 + lqs8;

    f32x4 acc[8][4] = {};
    half8 aA[4], aB[4], bA[4], bB[4];

    // prologue: tile 0 (seg0) both halves + tile 1 k0
    stage_half(&lds[0][0], Aq, mb, 0, tid);
    stage_half(&lds[2][0], Bh, nb, 0, tid);
    stage_half(&lds[1][0], Aq, mb, 32, tid);
    stage_half(&lds[3][0], Bh, nb, 32, tid);
    stage_half(&lds[4][0], Aq, mb, 64, tid);
    stage_half(&lds[6][0], Bh, nb, 64, tid);
    VMW(8);
    BAR();
    RDB(bA, 2);
    RDA(aA, 0, 0);

    for (int t = 0; t < NT - 2; ++t) {
        const int p = t & 1;
        const int t1 = t + 1, t2 = t + 2;
        const int sg1 = t1 >> 4, sg2 = t2 >> 4;
        const u16* a1 = (sg1 == 1) ? Al : Aq;
        const u16* b1 = (sg1 == 2) ? Bl : Bh;
        const u16* a2 = (sg2 == 1) ? Al : Aq;
        const u16* b2 = (sg2 == 2) ? Bl : Bh;
        const int k1 = ((t1 & 15) << 6) + 32;
        const int k2 = (t2 & 15) << 6;
        W0(p, stage_half(&lds[((p ^ 1) << 2) | 1][0], a1, mb, k1, tid), VMW(6));
        W1(p, stage_half(&lds[((p ^ 1) << 2) | 3][0], b1, nb, k1, tid));
        W2(p, stage_half(&lds[(p << 2) | 0][0], a2, mb, k2, tid), VMW(6));
        W3(p, stage_half(&lds[(p << 2) | 2][0], b2, nb, k2, tid));
    }
    {   // t = NT-2 = 46 (p = 0): stage tile 47 (seg2: Qh, Kl) k1 only
        const int k1 = ((47 & 15) << 6) + 32;
        W0(0, stage_half(&lds[(1 << 2) | 1][0], Aq, mb, k1, tid), VMW(6));
        W1(0, stage_half(&lds[(1 << 2) | 3][0], Bl, nb, k1, tid));
        W2(0, NOP_, VMW(4));
        W3(0, NOP_);
    }
    {   // t = NT-1 = 47 (p = 1): drain
        W0(1, NOP_, VMW(0));
        W1(1, NOP_);
        W2(1, NOP_, NOP_);
        W3L();
    }

    // epilogue: SC[z-local][m][n] fp32
    size_t sc_limit = (size_t)gridDim.z * S_ * S_;
#pragma unroll
    for (int j = 0; j < 4; ++j) {
        int n_g = nb + wn + j * 16 + lr;
#pragma unroll
        for (int i = 0; i < 8; ++i) {
            int m0 = mb + wm + i * 16 + lq * 4;
#pragma unroll
            for (int r = 0; r < 4; ++r) {
                size_t idx = ((size_t)blockIdx.z * S_ + m0 + r) * S_ + n_g;
                if (idx < sc_limit) SC[idx] = acc[i][j][r];
            }
        }
    }
}

// ---------------- GEMM2 fallback (128^2, zc<4 only) ----------------
__global__ __launch_bounds__(256) void k_gemm2(
    const u16* __restrict__ Qh, const u16* __restrict__ Ql,
    const u16* __restrict__ Kh, const u16* __restrict__ Kl,
    float* __restrict__ SC, int zbase) {
    __shared__ __attribute__((aligned(16))) u16 sAh[128 * LP], sAl[128 * LP],
                                                sBh[128 * LP], sBl[128 * LP];
    int tid = threadIdx.x;
    int nb = blockIdx.x * 128, mb = blockIdx.y * 128;
    int z = zbase + blockIdx.z;
    const u16* Ah = Qh + (size_t)z * S_ * KC;
    const u16* Al = Ql + (size_t)z * S_ * KC;
    const u16* Bh = Kh + (size_t)z * S_ * KC;
    const u16* Bl = Kl + (size_t)z * S_ * KC;
    int lane = tid & 63, wave = tid >> 6;
    int wm = (wave >> 1) * 64, wn = (wave & 1) * 64;
    int lr = lane & 15, lq = lane >> 4;
    f32x4 acc[4][4] = {};

    for (int k0 = 0; k0 < KC; k0 += 32) {
        __syncthreads();
        stage_dma(Ah, KC, mb, k0, sAh, tid);
        stage_dma(Al, KC, mb, k0, sAl, tid);
        stage_dma(Bh, KC, nb, k0, sBh, tid);
        stage_dma(Bl, KC, nb, k0, sBl, tid);
        __syncthreads();
        half8 ah[4], al[4], bh[4], bl[4];
#pragma unroll
        for (int i = 0; i < 4; ++i) {
            int ra = wm + i * 16 + lr;
            ah[i] = *(const half8*)&sAh[ra * LP + lq * 8];
            al[i] = *(const half8*)&sAl[ra * LP + lq * 8];
            int rb = wn + i * 16 + lr;
            bh[i] = *(const half8*)&sBh[rb * LP + lq * 8];
            bl[i] = *(const half8*)&sBl[rb * LP + lq * 8];
        }
#pragma unroll
        for (int i = 0; i < 4; ++i)
#pragma unroll
            for (int j = 0; j < 4; ++j) {
                acc[i][j] = mfma16(ah[i], bh[j], acc[i][j]);
                acc[i][j] = mfma16(al[i], bh[j], acc[i][j]);
                acc[i][j] = mfma16(ah[i], bl[j], acc[i][j]);
            }
    }

    size_t sc_limit = (size_t)gridDim.z * S_ * S_;
#pragma unroll
    for (int j = 0; j < 4; ++j) {
        int t = nb + wn + j * 16 + lr;
#pragma unroll
        for (int i = 0; i < 4; ++i) {
            int s0 = mb + wm + i * 16 + lq * 4;
#pragma unroll
            for (int r = 0; r < 4; ++r) {
                size_t idx = ((size_t)blockIdx.z * S_ + s0 + r) * S_ + t;
                if (idx < sc_limit) SC[idx] = acc[i][j][r];
            }
        }
    }
}

// ---------------- softmax: SC fp32 -> AT fp16 ----------------
__global__ __launch_bounds__(256) void k_softmax(const float* __restrict__ SC,
                                                 u16* __restrict__ AT, int zbase) {
    int row = blockIdx.x;
    const float* src = SC + (size_t)row * S_;
    size_t drow = (size_t)zbase * S_ + row;
    u16* dst = AT + drow * S_;
    int tid = threadIdx.x;
    float v[8];
#pragma unroll
    for (int i = 0; i < 8; ++i) v[i] = src[tid + i * 256];
    float m = v[0];
#pragma unroll
    for (int i = 1; i < 8; ++i) m = fmaxf(m, v[i]);
    for (int off = 32; off > 0; off >>= 1) m = fmaxf(m, __shfl_down(m, off));
    __shared__ float redm[4], reds[4];
    if ((tid & 63) == 0) redm[tid >> 6] = m;
    __syncthreads();
    m = fmaxf(fmaxf(redm[0], redm[1]), fmaxf(redm[2], redm[3]));
    float s = 0.f;
#pragma unroll
    for (int i = 0; i < 8; ++i) { v[i] = __expf(v[i] - m); s += v[i]; }
    for (int off = 32; off > 0; off >>= 1) s += __shfl_down(s, off);
    if ((tid & 63) == 0) reds[tid >> 6] = s;
    __syncthreads();
    float inv = 1.0f / (reds[0] + reds[1] + reds[2] + reds[3]);
    if (drow * S_ + 2047 < AT_ELEMS) {
#pragma unroll
        for (int i = 0; i < 8; ++i) dst[tid + i * 256] = f2h(v[i] * inv);
    }
}

// ---------------- GEMM3: out = attn @ Vcat (plain fp16), planar epilogue ----------------
__global__ __launch_bounds__(256) void k_gemm3(
    const u16* __restrict__ AT, const u16* __restrict__ VT,
    float* __restrict__ out, int out_size, int full) {
    __shared__ __attribute__((aligned(16))) u16 sA[128 * LP], sB[128 * LP];
    int tid = threadIdx.x;
    int nb = blockIdx.x * 128, mb = blockIdx.y * 128, z = blockIdx.z;
    const u16* Abase = AT + (size_t)z * S_ * S_;
    const u16* Bbase = VT + (size_t)z * KC * S_;
    int lane = tid & 63, wave = tid >> 6;
    int wm = (wave >> 1) * 64, wn = (wave & 1) * 64;
    int lr = lane & 15, lq = lane >> 4;
    f32x4 acc[4][4] = {};

    for (int k0 = 0; k0 < S_; k0 += 32) {
        __syncthreads();
        stage_dma(Abase, S_, mb, k0, sA, tid);
        stage_dma(Bbase, S_, nb, k0, sB, tid);
        __syncthreads();
        half8 a[4], b[4];
#pragma unroll
        for (int i = 0; i < 4; ++i) {
            a[i] = *(const half8*)&sA[(wm + i * 16 + lr) * LP + lq * 8];
            b[i] = *(const half8*)&sB[(wn + i * 16 + lr) * LP + lq * 8];
        }
#pragma unroll
        for (int i = 0; i < 4; ++i)
#pragma unroll
            for (int j = 0; j < 4; ++j)
                acc[i][j] = mfma16(a[i], b[j], acc[i][j]);
    }

#pragma unroll
    for (int j = 0; j < 4; ++j) {
        int f = nb + wn + j * 16 + lr;
#pragma unroll
        for (int i = 0; i < 4; ++i) {
            int s0 = mb + wm + i * 16 + lq * 4;
#pragma unroll
            for (int r = 0; r < 4; ++r) {
                size_t base = ((size_t)z * S_ + s0 + r) * D_;
                if (f < D_) {
                    size_t o = base + f;
                    if (o < (size_t)out_size) out[o] = acc[i][j][r];
                } else if (full) {
                    size_t o = (size_t)RE_PLANE + base + (f - D_);
                    if (o < (size_t)out_size) out[o] = acc[i][j][r];
                }
            }
        }
    }
}

// ---------------- launch ----------------

extern "C" void kernel_launch(void* const* d_in, const int* in_sizes, int n_in,
                              void* d_out, int out_size, void* d_ws, size_t ws_size,
                              hipStream_t stream) {
    (void)in_sizes; (void)n_in;
    const float* xr  = (const float*)d_in[0];
    const float* xi  = (const float*)d_in[1];
    const float* Wqr = (const float*)d_in[2];
    const float* Wqi = (const float*)d_in[3];
    const float* bqr = (const float*)d_in[4];
    const float* bqi = (const float*)d_in[5];
    const float* Wkr = (const float*)d_in[6];
    const float* Wki = (const float*)d_in[7];
    const float* bkr = (const float*)d_in[8];
    const float* bki = (const float*)d_in[9];
    const float* Wvr = (const float*)d_in[10];
    const float* Wvi = (const float*)d_in[11];
    const float* bvr = (const float*)d_in[12];
    const float* bvi = (const float*)d_in[13];
    float* out = (float*)d_out;

    constexpr size_t SZ_X  = X_ELEMS * 2;          // 16 MiB each (Xh, Xl)
    constexpr size_t SZ_W  = W_ELEMS * 2;          // 6 MiB
    constexpr size_t SZ_BC = (size_t)N1 * 4;
    constexpr size_t SZ_QK = QK_ELEMS * 2;         // 16 MiB each (Qh,Ql,Kh,Kl)
    constexpr size_t SZ_VT = VT_ELEMS * 2;         // 16 MiB
    constexpr size_t SZ_SC_B = (size_t)S_ * S_ * 4;  // 16 MiB per batch

    char* p = (char*)d_ws;
    size_t off = 0;
    auto take = [&](size_t sz) {
        char* r = p + off;
        off += (sz + 255) & ~(size_t)255;
        return r;
    };
    u16*   Xh = (u16*)take(SZ_X);
    u16*   Xl = (u16*)take(SZ_X);
    u16*   Wh = (u16*)take(SZ_W);
    float* bc = (float*)take(SZ_BC);
    u16*   Qh = (u16*)take(SZ_QK);
    u16*   Ql = (u16*)take(SZ_QK);
    u16*   Kh = (u16*)take(SZ_QK);
    u16*   Kl = (u16*)take(SZ_QK);
    u16*   VT = (u16*)take(SZ_VT);
    u16*   AT = Xh;  // aliases Xh+Xl (32 MiB, dead after gemm1); no Qh overlap
    float* SC = (float*)(p + off);

    int nz = 0;
    if (ws_size > off) nz = (int)((ws_size - off) / SZ_SC_B);
    if (nz > B_) nz = B_;
    if (nz < 1) {
        k_diag<<<16, 256, 0, stream>>>(out, out_size, 1000.0f + (float)(ws_size >> 20));
        return;
    }

    int full = (out_size >= 2 * RE_PLANE) ? 1 : 0;

    k_prep<<<16384 + 12288 + 12, 256, 0, stream>>>(
        xr, xi, Wqr, Wqi, Wkr, Wki, Wvr, Wvi,
        bqr, bqi, bkr, bki, bvr, bvi, Xh, Xl, Wh, bc);
    k_gemm1<<<dim3(12, 32), 512, 0, stream>>>(Xh, Xl, Wh, bc, Qh, Ql, Kh, Kl, VT);

    for (int z0 = 0; z0 < B_; z0 += nz) {
        int zc = (B_ - z0 < nz) ? (B_ - z0) : nz;
        if (zc == B_) {
            k_gemm2_256<<<dim3(S_ / 256, S_ / 256, zc), 512, 0, stream>>>(
                Qh, Ql, Kh, Kl, SC, z0);
        } else {
            k_gemm2<<<dim3(S_ / 128, S_ / 128, zc), 256, 0, stream>>>(
                Qh, Ql, Kh, Kl, SC, z0);
        }
        k_softmax<<<zc * S_, 256, 0, stream>>>(SC, AT, z0);
    }
    k_gemm3<<<dim3(KC / 128, S_ / 128, B_), 256, 0, stream>>>(AT, VT, out, out_size, full);
}